// Round 19
// baseline (142.217 us; speedup 1.0000x reference)
//
#include <hip/hip_runtime.h>
#include <math.h>

#define NCAM 6
#define FHh 16
#define FWw 44
#define PIX 704            // FHh*FWw
#define FCc 128
#define DB 48
#define C3 177             // DB + 1 + 128
#define KCONV 1152         // FCc*9
#define NG 4224            // NCAM*PIX
#define BEVN 10000
#define NSPLIT 3
#define SG 1408            // gaussians per split (22 groups of 64)
#define TH_LOG (-5.5412635f)   // -ln(255): alpha>=1/255  <=>  pw+lop >= TH_LOG

// ---- ws layout (float offsets) ----
#define OFF_WT1    0                           // bf16 hi/lo ushorts (147456 floats)
#define OFF_WT2    147456
#define OFF_WT3    294912                      // bf16 hi/lo [192][128] (24576 floats)
#define OFF_GEO    319488                      // [6*48*704][2]
#define OFF_X1     724992                      // [6][128][704]
#define OFF_X2     1265664
#define OFF_X3     1806336                     // [6][177][704]
#define OFF_PRM    4716672                     // float4 [NG]: py,px,qc,qa
#define OFF_PRM2   4733568                     // float2 [NG]: qb,lop
#define OFF_FEATT  4742016                     // [NG][128] f32
#define OFF_SF     0                           // [NSPLIT][BEVN][128] raster partials (aliases convs)
#define OFF_SP     3840000                     // [NSPLIT][BEVN] local transmittance
// end = 5,282,688 floats = 21.1 MiB

typedef __attribute__((ext_vector_type(8))) short bf16x8;
typedef __attribute__((ext_vector_type(4))) float f32x4;
typedef __attribute__((ext_vector_type(4))) int i32x4;
typedef __attribute__((ext_vector_type(2))) int i32x2;

__device__ __forceinline__ unsigned short f2bf(float x) {
  unsigned u = __float_as_uint(x);
  return (unsigned short)((u + 0x7FFF + ((u >> 16) & 1)) >> 16);
}
__device__ __forceinline__ float bf2f(unsigned short h) {
  return __uint_as_float(((unsigned)h) << 16);
}

__device__ __forceinline__ void inv3(const float* A, float* I) {
  float a=A[0],b=A[1],c=A[2],d=A[3],e=A[4],f=A[5],g=A[6],h=A[7],i=A[8];
  float c0 = e*i - f*h, c1 = f*g - d*i, c2 = d*h - e*g;
  float det = a*c0 + b*c1 + c*c2;
  float id = 1.f/det;
  I[0]=c0*id; I[1]=(c*h-b*i)*id; I[2]=(b*f-c*e)*id;
  I[3]=c1*id; I[4]=(a*i-c*g)*id; I[5]=(c*d-a*f)*id;
  I[6]=c2*id; I[7]=(b*g-a*h)*id; I[8]=(a*e-b*d)*id;
}

// fused: blocks [0,792) = geometry; [792, 1368) = weight transform
__global__ void k_prep(const float* __restrict__ rot, const float* __restrict__ intr,
                       const float* __restrict__ post_rot,
                       const float* __restrict__ trans, const float* __restrict__ post_trans,
                       const float* __restrict__ w1, const float* __restrict__ w2,
                       const float* __restrict__ w3, float* __restrict__ ws) {
  if (blockIdx.x < 792) {
    __shared__ float sm[NCAM][24];
    if (threadIdx.x < NCAM) {
      int n = threadIdx.x;
      float ip[9], ii[9];
      inv3(post_rot + n*9, ip);
      inv3(intr + n*9, ii);
      const float* R = rot + n*9;
      for (int j = 0; j < 9; ++j) sm[n][j] = ip[j];
      for (int r = 0; r < 3; ++r)
        for (int c = 0; c < 3; ++c) {
          float s = 0.f;
          for (int k = 0; k < 3; ++k) s += R[r*3+k]*ii[k*3+c];
          sm[n][9 + r*3 + c] = s;
        }
    }
    __syncthreads();
    int idx = blockIdx.x*256 + threadIdx.x;
    if (idx >= NCAM*DB*PIX) return;
    int n = idx / (DB*PIX);
    int rem = idx % (DB*PIX);
    int d = rem / PIX;
    int hw = rem % PIX;
    int h = hw / FWw, w = hw % FWw;
    float fx = w * (351.0f/43.0f);
    float fy = h * (127.0f/15.0f);
    float fz = 1.0f + (float)d;
    const float* pt = post_trans + n*3;
    float v0 = fx - pt[0], v1 = fy - pt[1], v2 = fz - pt[2];
    const float* m = sm[n];
    float x = m[0]*v0 + m[1]*v1 + m[2]*v2;
    float y = m[3]*v0 + m[4]*v1 + m[5]*v2;
    float z = m[6]*v0 + m[7]*v1 + m[8]*v2;
    float q0 = x*z, q1 = y*z, q2 = z;
    const float* c = m + 9;
    const float* t = trans + n*3;
    float gx = c[0]*q0 + c[1]*q1 + c[2]*q2 + t[0];
    float gy = c[3]*q0 + c[4]*q1 + c[5]*q2 + t[1];
    ((float2*)(ws + OFF_GEO))[idx] = make_float2(gx, gy);
  } else {
    int e = (blockIdx.x - 792)*256 + threadIdx.x;
    if (e < 147456) {
      float v1 = w1[e], v2 = w2[e];
      unsigned short h1 = f2bf(v1), h2 = f2bf(v2);
      unsigned short l1 = f2bf(v1 - bf2f(h1)), l2 = f2bf(v2 - bf2f(h2));
      unsigned short* wt1 = (unsigned short*)(ws + OFF_WT1);
      unsigned short* wt2 = (unsigned short*)(ws + OFF_WT2);
      wt1[e] = h1; wt1[147456 + e] = l1;
      wt2[e] = h2; wt2[147456 + e] = l2;
    }
    if (e < 192*128) {                   // conv3: [oc<192][k<128], zero-pad oc>=177
      int oc = e >> 7, k = e & 127;
      float v = (oc < C3) ? w3[oc*FCc + k] : 0.f;
      unsigned short h = f2bf(v);
      unsigned short* wt3 = (unsigned short*)(ws + OFF_WT3);
      wt3[e] = h; wt3[24576 + e] = f2bf(v - bf2f(h));
    }
  }
}

#define LROW 20   // dwords per LDS row: 32 bf16 = 16 dw + 4 pad

// bf16x3 MFMA im2col GEMM, 3x3 convs. KSPLIT=1, 32oc x 32px tile, 36 K-steps.
// 256 thr = 4 waves, each wave one 16x16 C quadrant (3 MFMA/step).
// BN + ReLU fused in the epilogue -> writes X directly (no partials, no epi).
__global__ __launch_bounds__(256) void k_gemm_mfma32(
    const float* __restrict__ in, const float* ws, int woff,
    const float* __restrict__ cb, const float* __restrict__ g,
    const float* __restrict__ be, const float* __restrict__ mn,
    const float* __restrict__ vr, float* __restrict__ outbuf)
{
  __shared__ int alds[2][32*LROW];
  __shared__ int blds[2][32*LROW];
  int tid = threadIdx.x;
  int px0 = blockIdx.x * 32;
  int oc0 = blockIdx.y * 32;
  int n = blockIdx.z;
  const unsigned short* whi = (const unsigned short*)(ws + woff);
  const unsigned short* wlo = whi + 147456;
  const float* inn = in + (size_t)n*FCc*PIX;
  int wv = tid >> 6, lane = tid & 63;
  int a_oc = tid >> 3, a_kq = tid & 7;      // A stage: 32 oc x 8 k-quads(4)
  int b_px = tid & 31, b_kq = tid >> 5;     // B stage: 32 px x 8 k-quads(4)
  int p = px0 + b_px; int b_y = p / FWw, b_x = p - b_y*FWw;

  i32x2 pa_h, pa_l; float bv[4];
  auto issueA = [&](int s) {
    size_t gi = (size_t)(oc0 + a_oc)*KCONV + (s*32 + a_kq*4);
    pa_h = *(const i32x2*)(whi + gi);
    pa_l = *(const i32x2*)(wlo + gi);
  };
  auto issueB = [&](int s) {
    #pragma unroll
    for (int j = 0; j < 4; ++j) {
      int k = s*32 + b_kq*4 + j;
      int ic = k / 9, tap = k - ic*9;
      int ky = tap / 3, kx = tap - ky*3;
      int yy = b_y + ky - 1, xx = b_x + kx - 1;
      float v = 0.f;
      if ((unsigned)yy < FHh && (unsigned)xx < FWw) v = inn[(size_t)ic*PIX + yy*FWw + xx];
      bv[j] = v;
    }
  };

  f32x4 acc = {0.f,0.f,0.f,0.f};
  int ocr = (wv >> 1) * 16, pxr = (wv & 1) * 16;
  int dq = (lane >> 4) * 4;
  int rA = (ocr + (lane & 15)) * LROW + dq;
  int rB = (pxr + (lane & 15)) * LROW + dq;
  int aw = a_oc*LROW + a_kq*2;
  int bw = b_px*LROW + b_kq*2;

  issueA(0); issueB(0);
  for (int s = 0; s < 36; ++s) {
    __syncthreads();
    *(i32x2*)&alds[0][aw] = pa_h;
    *(i32x2*)&alds[1][aw] = pa_l;
    {
      i32x2 vh, vl;
      int th[4], tl[4];
      #pragma unroll
      for (int j = 0; j < 4; ++j) {
        unsigned short h = f2bf(bv[j]);
        th[j] = h; tl[j] = f2bf(bv[j] - bf2f(h));
      }
      vh.x = th[0]|(th[1]<<16); vh.y = th[2]|(th[3]<<16);
      vl.x = tl[0]|(tl[1]<<16); vl.y = tl[2]|(tl[3]<<16);
      *(i32x2*)&blds[0][bw] = vh;
      *(i32x2*)&blds[1][bw] = vl;
    }
    __syncthreads();
    if (s < 35) { issueA(s+1); issueB(s+1); }
    bf16x8 ah = *(bf16x8*)&alds[0][rA];
    bf16x8 al = *(bf16x8*)&alds[1][rA];
    bf16x8 bh = *(bf16x8*)&blds[0][rB];
    bf16x8 bl = *(bf16x8*)&blds[1][rB];
    acc = __builtin_amdgcn_mfma_f32_16x16x32_bf16(ah, bh, acc, 0, 0, 0);
    acc = __builtin_amdgcn_mfma_f32_16x16x32_bf16(ah, bl, acc, 0, 0, 0);
    acc = __builtin_amdgcn_mfma_f32_16x16x32_bf16(al, bh, acc, 0, 0, 0);
  }
  // epilogue: C col(px)=lane&15, row(oc)=(lane>>4)*4+i; BN+ReLU fused
  int ocb = oc0 + ocr + ((lane >> 4) << 2);
  int pxb = px0 + pxr + (lane & 15);
  #pragma unroll
  for (int i = 0; i < 4; ++i) {
    int oc = ocb + i;
    float inv = g[oc] * rsqrtf(vr[oc] + 1e-3f);
    float sh = (cb[oc] - mn[oc]) * inv + be[oc];
    outbuf[(size_t)(n*FCc + oc)*PIX + pxb] = fmaxf(acc[i]*inv + sh, 0.f);
  }
}

// bf16x3 MFMA GEMM for conv3 (1x1, K=128, bias fused, direct X3 write).
__global__ __launch_bounds__(256) void k_gemm_mfma3(
    const float* __restrict__ in, const float* ws,
    const float* __restrict__ bias, float* __restrict__ outbuf)
{
  __shared__ int alds[2][64*LROW];
  __shared__ int blds[2][64*LROW];
  int tid = threadIdx.x;
  int px0 = blockIdx.x * 64;
  int oc0 = blockIdx.y * 64;
  int n = blockIdx.z;
  const unsigned short* whi = (const unsigned short*)(ws + OFF_WT3);
  const unsigned short* wlo = whi + 24576;
  const float* inn = in + (size_t)n*FCc*PIX;
  int wv = tid >> 6, lane = tid & 63;
  int a_oc = tid >> 2, a_kq = tid & 3;
  int b_px = tid & 63, b_kq = tid >> 6;
  int p = px0 + b_px;

  i32x4 pa_h, pa_l; float bvv[8];
  auto issueA = [&](int s) {
    size_t gi = (size_t)(oc0 + a_oc)*128 + (s*32 + a_kq*8);
    pa_h = *(const i32x4*)(whi + gi);
    pa_l = *(const i32x4*)(wlo + gi);
  };
  auto issueB = [&](int s) {
    #pragma unroll
    for (int j = 0; j < 8; ++j) {
      int ic = s*32 + b_kq*8 + j;
      bvv[j] = inn[(size_t)ic*PIX + p];
    }
  };

  f32x4 a00 = {0.f,0.f,0.f,0.f}, a01 = a00, a10 = a00, a11 = a00;
  int ocr = (wv >> 1) * 32, pxr = (wv & 1) * 32;
  int dq = (lane >> 4) * 4;
  int rA0 = (ocr + (lane & 15)) * LROW + dq;
  int rA1 = rA0 + 16*LROW;
  int rB0 = (pxr + (lane & 15)) * LROW + dq;
  int rB1 = rB0 + 16*LROW;
  int aw = a_oc*LROW + a_kq*4;
  int bw = b_px*LROW + b_kq*4;

  issueA(0); issueB(0);
  for (int s = 0; s < 4; ++s) {
    __syncthreads();
    *(i32x4*)&alds[0][aw] = pa_h;
    *(i32x4*)&alds[1][aw] = pa_l;
    {
      i32x4 vh, vl;
      int th[8], tl[8];
      #pragma unroll
      for (int j = 0; j < 8; ++j) {
        unsigned short h = f2bf(bvv[j]);
        th[j] = h; tl[j] = f2bf(bvv[j] - bf2f(h));
      }
      vh.x = th[0]|(th[1]<<16); vh.y = th[2]|(th[3]<<16);
      vh.z = th[4]|(th[5]<<16); vh.w = th[6]|(th[7]<<16);
      vl.x = tl[0]|(tl[1]<<16); vl.y = tl[2]|(tl[3]<<16);
      vl.z = tl[4]|(tl[5]<<16); vl.w = tl[6]|(tl[7]<<16);
      *(i32x4*)&blds[0][bw] = vh;
      *(i32x4*)&blds[1][bw] = vl;
    }
    __syncthreads();
    if (s < 3) { issueA(s+1); issueB(s+1); }
    bf16x8 ah0 = *(bf16x8*)&alds[0][rA0], ah1 = *(bf16x8*)&alds[0][rA1];
    bf16x8 al0 = *(bf16x8*)&alds[1][rA0], al1 = *(bf16x8*)&alds[1][rA1];
    bf16x8 bh0 = *(bf16x8*)&blds[0][rB0], bh1 = *(bf16x8*)&blds[0][rB1];
    bf16x8 bl0 = *(bf16x8*)&blds[1][rB0], bl1 = *(bf16x8*)&blds[1][rB1];
    a00 = __builtin_amdgcn_mfma_f32_16x16x32_bf16(ah0, bh0, a00, 0, 0, 0);
    a01 = __builtin_amdgcn_mfma_f32_16x16x32_bf16(ah0, bh1, a01, 0, 0, 0);
    a10 = __builtin_amdgcn_mfma_f32_16x16x32_bf16(ah1, bh0, a10, 0, 0, 0);
    a11 = __builtin_amdgcn_mfma_f32_16x16x32_bf16(ah1, bh1, a11, 0, 0, 0);
    a00 = __builtin_amdgcn_mfma_f32_16x16x32_bf16(ah0, bl0, a00, 0, 0, 0);
    a01 = __builtin_amdgcn_mfma_f32_16x16x32_bf16(ah0, bl1, a01, 0, 0, 0);
    a10 = __builtin_amdgcn_mfma_f32_16x16x32_bf16(ah1, bl0, a10, 0, 0, 0);
    a11 = __builtin_amdgcn_mfma_f32_16x16x32_bf16(ah1, bl1, a11, 0, 0, 0);
    a00 = __builtin_amdgcn_mfma_f32_16x16x32_bf16(al0, bh0, a00, 0, 0, 0);
    a01 = __builtin_amdgcn_mfma_f32_16x16x32_bf16(al0, bh1, a01, 0, 0, 0);
    a10 = __builtin_amdgcn_mfma_f32_16x16x32_bf16(al1, bh0, a10, 0, 0, 0);
    a11 = __builtin_amdgcn_mfma_f32_16x16x32_bf16(al1, bh1, a11, 0, 0, 0);
  }
  int ocb = oc0 + ocr + ((lane >> 4) << 2);
  int pxb = px0 + pxr + (lane & 15);
  #pragma unroll
  for (int i = 0; i < 4; ++i) {
    int o0 = ocb + i, o1 = ocb + 16 + i;
    if (o0 < C3) {
      float b = bias[o0];
      outbuf[(size_t)(n*C3 + o0)*PIX + pxb]      = a00[i] + b;
      outbuf[(size_t)(n*C3 + o0)*PIX + pxb + 16] = a01[i] + b;
    }
    if (o1 < C3) {
      float b = bias[o1];
      outbuf[(size_t)(n*C3 + o1)*PIX + pxb]      = a10[i] + b;
      outbuf[(size_t)(n*C3 + o1)*PIX + pxb + 16] = a11[i] + b;
    }
  }
}

__global__ void k_moments(float* __restrict__ ws) {
  int wid  = (blockIdx.x * 256 + threadIdx.x) >> 6;
  int lane = threadIdx.x & 63;
  int n = wid / PIX, hw = wid % PIX;
  const float* x3 = ws + OFF_X3 + (size_t)n*C3*PIX + hw;
  float logit = (lane < DB) ? x3[(size_t)lane*PIX] : -1e30f;
  float mx = logit;
  for (int off = 1; off < 64; off <<= 1) mx = fmaxf(mx, __shfl_xor(mx, off));
  float e = (lane < DB) ? expf(logit - mx) : 0.f;
  float s = e;
  for (int off = 1; off < 64; off <<= 1) s += __shfl_xor(s, off);
  float p = e / s;
  float gx = 0.f, gy = 0.f;
  if (lane < DB) {
    float2 g2 = ((const float2*)(ws + OFF_GEO))[(size_t)(n*DB + lane)*PIX + hw];
    gx = g2.x; gy = g2.y;
  }
  float sx = p*gx;
  for (int off = 1; off < 64; off <<= 1) sx += __shfl_xor(sx, off);
  float sy = p*gy;
  for (int off = 1; off < 64; off <<= 1) sy += __shfl_xor(sy, off);
  float dx = gx - sx, dy = gy - sy;
  float c00 = p*dx*dx, c01 = p*dx*dy, c11 = p*dy*dy;
  for (int off = 1; off < 64; off <<= 1) c00 += __shfl_xor(c00, off);
  for (int off = 1; off < 64; off <<= 1) c01 += __shfl_xor(c01, off);
  for (int off = 1; off < 64; off <<= 1) c11 += __shfl_xor(c11, off);
  float opl = x3[(size_t)DB*PIX];
  float opac = 1.f / (1.f + expf(-opl));
  float a = c11*(1.f/9.f) + 0.3f;
  float b = c01*(1.f/9.f);
  float c = c00*(1.f/9.f) + 0.3f;
  float py = 50.f - sy;
  float px = 50.f - sx;
  float det = a*c - b*b;
  float op = (opac > 0.05f) ? opac : 0.f;
  float invd = 1.f;
  if (det > 0.f) invd = 1.f/det; else op = 0.f;
  if (lane == 0) {
    float lop = (op > 0.f) ? logf(op) : -1e30f;   // log-space opacity
    ((float4*)(ws + OFF_PRM))[wid]  = make_float4(py, px, -0.5f*c*invd, -0.5f*a*invd);
    ((float2*)(ws + OFF_PRM2))[wid] = make_float2(b*invd, lop);
  }
  float* ft = ws + OFF_FEATT + (size_t)wid*128;
  ft[lane]      = x3[(size_t)(DB + 1 + lane)*PIX];
  ft[lane + 64] = x3[(size_t)(DB + 1 + lane + 64)*PIX];
}

template<int CTRL, int RMASK>
__device__ __forceinline__ float dpp_mul(float v) {
  int t = __builtin_amdgcn_update_dpp(0x3f800000, __float_as_int(v), CTRL, RMASK, 0xF, false);
  return v * __int_as_float(t);
}

// Split-K raster (R14 measured-best config): block = 8 pixels x 1 split of
// 1408 gaussians (22 groups), single 33.8KB LDS stage, log-reject + DPP scan
// + 8-wide batched f32 feature gather. Partials -> k_combine.
__global__ __launch_bounds__(512) void k_raster(const float* __restrict__ ws,
                                                float* __restrict__ wsout) {
  __shared__ float4 s4[SG];
  __shared__ float2 s2[SG];
  int lane = threadIdx.x & 63, wv = threadIdx.x >> 6;
  int split = blockIdx.x / 1250;
  int pxb   = blockIdx.x % 1250;
  int pix = pxb * 8 + wv;
  float yi = (float)(pix / 100), xi = (float)(pix % 100);
  int gbase = split * SG;
  const float4* prm4 = (const float4*)(ws + OFF_PRM) + gbase;
  const float2* prm2 = (const float2*)(ws + OFF_PRM2) + gbase;
  const float2* ft = (const float2*)(ws + OFF_FEATT);
  for (int i = threadIdx.x; i < SG; i += 512) {
    s4[i] = prm4[i];
    s2[i] = prm2[i];
  }
  __syncthreads();
  float T = 1.f, ax = 0.f, ay = 0.f;
  for (int gl = 0; gl < SG; gl += 64) {
    float4 c4 = s4[gl + lane];
    float2 c2 = s2[gl + lane];
    float dyv = c4.x - yi, dxv = c4.y - xi;
    float pw = c4.z*dyv*dyv + c4.w*dxv*dxv + c2.x*dyv*dxv;
    float t  = pw + c2.y;                       // pw + log(op)
    bool hit = (t >= TH_LOG);
    unsigned long long m0 = __ballot(hit);
    if (m0) {
      float alpha = __expf(fminf(t, c2.y));     // op*exp(min(pw,0))
      alpha = fminf(alpha, 0.99f);
      alpha = hit ? alpha : 0.f;
      float P = 1.f - alpha;
      P = dpp_mul<0x111, 0xF>(P);
      P = dpp_mul<0x112, 0xF>(P);
      P = dpp_mul<0x114, 0xF>(P);
      P = dpp_mul<0x118, 0xF>(P);
      P = dpp_mul<0x142, 0xA>(P);
      P = dpp_mul<0x143, 0xC>(P);
      float E = __int_as_float(__builtin_amdgcn_update_dpp(
                  0x3f800000, __float_as_int(P), 0x138, 0xF, 0xF, false));
      float w = alpha * T * E;
      T *= __int_as_float(__builtin_amdgcn_readlane(__float_as_int(P), 63));
      unsigned long long mask = __ballot(w > 1e-9f);
      int g0 = gbase + gl;
      while (mask) {
        int jj[8];
        #pragma unroll
        for (int b = 0; b < 8; ++b) {
          if (mask) { jj[b] = __builtin_ctzll(mask); mask &= mask - 1ull; }
          else jj[b] = -1;
        }
        float2 fb[8]; float wb[8];
        #pragma unroll
        for (int b = 0; b < 8; ++b) {
          int j = (jj[b] >= 0) ? jj[b] : jj[0];
          fb[b] = ft[(size_t)(g0 + j)*64 + lane];
          wb[b] = (jj[b] >= 0)
            ? __int_as_float(__builtin_amdgcn_readlane(__float_as_int(w), jj[b]))
            : 0.f;
        }
        #pragma unroll
        for (int b = 0; b < 8; ++b) { ax += wb[b]*fb[b].x; ay += wb[b]*fb[b].y; }
      }
      if (T < 1e-7f) break;                     // local exit (error < 1e-7)
    }
  }
  float* sf = wsout + OFF_SF + ((size_t)split*BEVN + pix)*128;
  sf[2*lane]   = ax;
  sf[2*lane+1] = ay;
  if (lane == 0) (wsout + OFF_SP)[split*BEVN + pix] = T;
}

// ordered combine: F = F0 + T0*F1 + T0*T1*F2
__global__ __launch_bounds__(512) void k_combine(const float* __restrict__ ws,
                                                 float* __restrict__ out) {
  int lane = threadIdx.x & 63, wv = threadIdx.x >> 6;
  int pix = blockIdx.x * 8 + wv;
  const float* sp = ws + OFF_SP;
  float P0 = sp[pix], P1 = sp[BEVN + pix];
  const float2* f0 = (const float2*)(ws + OFF_SF + (size_t)pix*128);
  const float2* f1 = (const float2*)(ws + OFF_SF + ((size_t)BEVN + pix)*128);
  const float2* f2 = (const float2*)(ws + OFF_SF + ((size_t)2*BEVN + pix)*128);
  float2 a = f0[lane], b = f1[lane], c = f2[lane];
  float w1 = P0, w2 = P0*P1;
  float ox = a.x + w1*b.x + w2*c.x;
  float oy = a.y + w1*b.y + w2*c.y;
  out[(size_t)(2*lane)*BEVN + pix]   = ox;
  out[(size_t)(2*lane+1)*BEVN + pix] = oy;
}

extern "C" void kernel_launch(void* const* d_in, const int* in_sizes, int n_in,
                              void* d_out, int out_size, void* d_ws, size_t ws_size,
                              hipStream_t stream) {
  const float* rot        = (const float*)d_in[0];
  const float* trans      = (const float*)d_in[1];
  const float* intr       = (const float*)d_in[2];
  const float* post_rot   = (const float*)d_in[3];
  const float* post_trans = (const float*)d_in[4];
  const float* img        = (const float*)d_in[5];
  const float* w1  = (const float*)d_in[6];
  const float* b1  = (const float*)d_in[7];
  const float* g1  = (const float*)d_in[8];
  const float* be1 = (const float*)d_in[9];
  const float* m1  = (const float*)d_in[10];
  const float* v1  = (const float*)d_in[11];
  const float* w2  = (const float*)d_in[12];
  const float* b2  = (const float*)d_in[13];
  const float* g2  = (const float*)d_in[14];
  const float* be2 = (const float*)d_in[15];
  const float* m2  = (const float*)d_in[16];
  const float* v2  = (const float*)d_in[17];
  const float* w3  = (const float*)d_in[18];
  const float* b3  = (const float*)d_in[19];
  float* ws  = (float*)d_ws;
  float* out = (float*)d_out;

  k_prep<<<1368, 256, 0, stream>>>(rot, intr, post_rot, trans, post_trans,
                                   w1, w2, w3, ws);

  // conv1: bf16x3 MFMA, KSPLIT=1, BN+ReLU fused
  k_gemm_mfma32<<<dim3(22,4,6), 256, 0, stream>>>(img, ws, OFF_WT1,
                                                  b1, g1, be1, m1, v1, ws+OFF_X1);
  // conv2
  k_gemm_mfma32<<<dim3(22,4,6), 256, 0, stream>>>(ws+OFF_X1, ws, OFF_WT2,
                                                  b2, g2, be2, m2, v2, ws+OFF_X2);
  // conv3: 1x1, K=128, bf16x3 MFMA, bias fused, direct X3 write
  k_gemm_mfma3<<<dim3(11,3,6), 256, 0, stream>>>(ws+OFF_X2, ws, b3, ws+OFF_X3);

  k_moments<<<1056, 256, 0, stream>>>(ws);
  k_raster<<<3750, 512, 0, stream>>>(ws, ws);
  k_combine<<<1250, 512, 0, stream>>>(ws, out);
}

// Round 20
// 119.787 us; speedup vs baseline: 1.1873x; 1.1873x over previous
//
#include <hip/hip_runtime.h>
#include <math.h>

#define NCAM 6
#define FHh 16
#define FWw 44
#define PIX 704            // FHh*FWw
#define FCc 128
#define DB 48
#define C3 177             // DB + 1 + 128
#define KCONV 1152         // FCc*9
#define NG 4224            // NCAM*PIX
#define BEVN 10000
#define NSPLIT 3
#define SG 1408            // gaussians per split (22 groups of 64)
#define TH_LOG (-5.5412635f)   // -ln(255): alpha>=1/255  <=>  pw+lop >= TH_LOG

// ---- ws layout (float offsets) ----
#define OFF_WT1    0                           // bf16 hi/lo ushorts (147456 floats)
#define OFF_WT2    147456
#define OFF_WT3    294912                      // bf16 hi/lo [192][128] (24576 floats)
#define OFF_GEO    319488                      // [6*48*704][2]
#define OFF_X1     724992                      // [6][128][704]
#define OFF_X2     1265664
#define OFF_X3     1806336                     // [6][177][704]
#define OFF_PART   2553984                     // [4][6][128][704] conv partials
#define OFF_PRM    4716672                     // float4 [NG]: py,px,qc,qa
#define OFF_PRM2   4733568                     // float2 [NG]: qb,lop
#define OFF_FEATT  4742016                     // [NG][128] f32
#define OFF_SF     0                           // [NSPLIT][BEVN][64] uints (packed bf16 partials)
#define OFF_SP     3840000                     // [NSPLIT][BEVN] local transmittance
// end = 5,282,688 floats = 21.1 MiB

typedef __attribute__((ext_vector_type(8))) short bf16x8;
typedef __attribute__((ext_vector_type(4))) float f32x4;
typedef __attribute__((ext_vector_type(4))) int i32x4;

__device__ __forceinline__ unsigned short f2bf(float x) {
  unsigned u = __float_as_uint(x);
  return (unsigned short)((u + 0x7FFF + ((u >> 16) & 1)) >> 16);
}
__device__ __forceinline__ float bf2f(unsigned short h) {
  return __uint_as_float(((unsigned)h) << 16);
}

__device__ __forceinline__ void inv3(const float* A, float* I) {
  float a=A[0],b=A[1],c=A[2],d=A[3],e=A[4],f=A[5],g=A[6],h=A[7],i=A[8];
  float c0 = e*i - f*h, c1 = f*g - d*i, c2 = d*h - e*g;
  float det = a*c0 + b*c1 + c*c2;
  float id = 1.f/det;
  I[0]=c0*id; I[1]=(c*h-b*i)*id; I[2]=(b*f-c*e)*id;
  I[3]=c1*id; I[4]=(a*i-c*g)*id; I[5]=(c*d-a*f)*id;
  I[6]=c2*id; I[7]=(b*g-a*h)*id; I[8]=(a*e-b*d)*id;
}

// fused: blocks [0,792) = geometry; [792, 1368) = weight transform
__global__ void k_prep(const float* __restrict__ rot, const float* __restrict__ intr,
                       const float* __restrict__ post_rot,
                       const float* __restrict__ trans, const float* __restrict__ post_trans,
                       const float* __restrict__ w1, const float* __restrict__ w2,
                       const float* __restrict__ w3, float* __restrict__ ws) {
  if (blockIdx.x < 792) {
    __shared__ float sm[NCAM][24];
    if (threadIdx.x < NCAM) {
      int n = threadIdx.x;
      float ip[9], ii[9];
      inv3(post_rot + n*9, ip);
      inv3(intr + n*9, ii);
      const float* R = rot + n*9;
      for (int j = 0; j < 9; ++j) sm[n][j] = ip[j];
      for (int r = 0; r < 3; ++r)
        for (int c = 0; c < 3; ++c) {
          float s = 0.f;
          for (int k = 0; k < 3; ++k) s += R[r*3+k]*ii[k*3+c];
          sm[n][9 + r*3 + c] = s;
        }
    }
    __syncthreads();
    int idx = blockIdx.x*256 + threadIdx.x;
    if (idx >= NCAM*DB*PIX) return;
    int n = idx / (DB*PIX);
    int rem = idx % (DB*PIX);
    int d = rem / PIX;
    int hw = rem % PIX;
    int h = hw / FWw, w = hw % FWw;
    float fx = w * (351.0f/43.0f);
    float fy = h * (127.0f/15.0f);
    float fz = 1.0f + (float)d;
    const float* pt = post_trans + n*3;
    float v0 = fx - pt[0], v1 = fy - pt[1], v2 = fz - pt[2];
    const float* m = sm[n];
    float x = m[0]*v0 + m[1]*v1 + m[2]*v2;
    float y = m[3]*v0 + m[4]*v1 + m[5]*v2;
    float z = m[6]*v0 + m[7]*v1 + m[8]*v2;
    float q0 = x*z, q1 = y*z, q2 = z;
    const float* c = m + 9;
    const float* t = trans + n*3;
    float gx = c[0]*q0 + c[1]*q1 + c[2]*q2 + t[0];
    float gy = c[3]*q0 + c[4]*q1 + c[5]*q2 + t[1];
    ((float2*)(ws + OFF_GEO))[idx] = make_float2(gx, gy);
  } else {
    int e = (blockIdx.x - 792)*256 + threadIdx.x;
    if (e < 147456) {
      float v1 = w1[e], v2 = w2[e];
      unsigned short h1 = f2bf(v1), h2 = f2bf(v2);
      unsigned short l1 = f2bf(v1 - bf2f(h1)), l2 = f2bf(v2 - bf2f(h2));
      unsigned short* wt1 = (unsigned short*)(ws + OFF_WT1);
      unsigned short* wt2 = (unsigned short*)(ws + OFF_WT2);
      wt1[e] = h1; wt1[147456 + e] = l1;
      wt2[e] = h2; wt2[147456 + e] = l2;
    }
    if (e < 192*128) {                   // conv3: [oc<192][k<128], zero-pad oc>=177
      int oc = e >> 7, k = e & 127;
      float v = (oc < C3) ? w3[oc*FCc + k] : 0.f;
      unsigned short h = f2bf(v);
      unsigned short* wt3 = (unsigned short*)(ws + OFF_WT3);
      wt3[e] = h; wt3[24576 + e] = f2bf(v - bf2f(h));
    }
  }
}

#define LROW 20   // dwords per LDS row: 32 bf16 = 16 dw + 4 pad

// bf16x3 MFMA im2col GEMM, 3x3 convs. Block 256 thr = 4 waves, 64oc x 64px,
// Kchunk 288 (9 steps of K=32). D = AhBh + AhBl + AlBh.
__global__ __launch_bounds__(256) void k_gemm_mfma(
    const float* __restrict__ in, const float* ws, float* __restrict__ part, int woff)
{
  __shared__ int alds[2][64*LROW];
  __shared__ int blds[2][64*LROW];
  int tid = threadIdx.x;
  int px0 = blockIdx.x * 64;
  int oc0 = blockIdx.y * 64;
  int z = blockIdx.z; int n = z >> 2, ks = z & 3;
  const unsigned short* whi = (const unsigned short*)(ws + woff);
  const unsigned short* wlo = whi + 147456;
  const float* inn = in + (size_t)n*FCc*PIX;
  int wv = tid >> 6, lane = tid & 63;
  int a_oc = tid >> 2, a_kq = tid & 3;
  int b_px = tid & 63, b_kq = tid >> 6;
  int p = px0 + b_px; int b_y = p / FWw, b_x = p - b_y*FWw;
  int k00 = ks * 288;

  i32x4 pa_h, pa_l; float bv[8];
  auto issueA = [&](int s) {
    size_t gi = (size_t)(oc0 + a_oc)*KCONV + (k00 + s*32 + a_kq*8);
    pa_h = *(const i32x4*)(whi + gi);
    pa_l = *(const i32x4*)(wlo + gi);
  };
  auto issueB = [&](int s) {
    #pragma unroll
    for (int j = 0; j < 8; ++j) {
      int k = k00 + s*32 + b_kq*8 + j;
      int ic = k / 9, tap = k - ic*9;
      int ky = tap / 3, kx = tap - ky*3;
      int yy = b_y + ky - 1, xx = b_x + kx - 1;
      float v = 0.f;
      if ((unsigned)yy < FHh && (unsigned)xx < FWw) v = inn[(size_t)ic*PIX + yy*FWw + xx];
      bv[j] = v;
    }
  };

  f32x4 a00 = {0.f,0.f,0.f,0.f}, a01 = a00, a10 = a00, a11 = a00;
  int ocr = (wv >> 1) * 32, pxr = (wv & 1) * 32;
  int dq = (lane >> 4) * 4;
  int rA0 = (ocr + (lane & 15)) * LROW + dq;
  int rA1 = rA0 + 16*LROW;
  int rB0 = (pxr + (lane & 15)) * LROW + dq;
  int rB1 = rB0 + 16*LROW;
  int aw = a_oc*LROW + a_kq*4;
  int bw = b_px*LROW + b_kq*4;

  issueA(0); issueB(0);
  for (int s = 0; s < 9; ++s) {
    __syncthreads();
    *(i32x4*)&alds[0][aw] = pa_h;
    *(i32x4*)&alds[1][aw] = pa_l;
    {
      i32x4 vh, vl;
      int th[8], tl[8];
      #pragma unroll
      for (int j = 0; j < 8; ++j) {
        unsigned short h = f2bf(bv[j]);
        th[j] = h; tl[j] = f2bf(bv[j] - bf2f(h));
      }
      vh.x = th[0]|(th[1]<<16); vh.y = th[2]|(th[3]<<16);
      vh.z = th[4]|(th[5]<<16); vh.w = th[6]|(th[7]<<16);
      vl.x = tl[0]|(tl[1]<<16); vl.y = tl[2]|(tl[3]<<16);
      vl.z = tl[4]|(tl[5]<<16); vl.w = tl[6]|(tl[7]<<16);
      *(i32x4*)&blds[0][bw] = vh;
      *(i32x4*)&blds[1][bw] = vl;
    }
    __syncthreads();
    if (s < 8) { issueA(s+1); issueB(s+1); }
    bf16x8 ah0 = *(bf16x8*)&alds[0][rA0], ah1 = *(bf16x8*)&alds[0][rA1];
    bf16x8 al0 = *(bf16x8*)&alds[1][rA0], al1 = *(bf16x8*)&alds[1][rA1];
    bf16x8 bh0 = *(bf16x8*)&blds[0][rB0], bh1 = *(bf16x8*)&blds[0][rB1];
    bf16x8 bl0 = *(bf16x8*)&blds[1][rB0], bl1 = *(bf16x8*)&blds[1][rB1];
    a00 = __builtin_amdgcn_mfma_f32_16x16x32_bf16(ah0, bh0, a00, 0, 0, 0);
    a01 = __builtin_amdgcn_mfma_f32_16x16x32_bf16(ah0, bh1, a01, 0, 0, 0);
    a10 = __builtin_amdgcn_mfma_f32_16x16x32_bf16(ah1, bh0, a10, 0, 0, 0);
    a11 = __builtin_amdgcn_mfma_f32_16x16x32_bf16(ah1, bh1, a11, 0, 0, 0);
    a00 = __builtin_amdgcn_mfma_f32_16x16x32_bf16(ah0, bl0, a00, 0, 0, 0);
    a01 = __builtin_amdgcn_mfma_f32_16x16x32_bf16(ah0, bl1, a01, 0, 0, 0);
    a10 = __builtin_amdgcn_mfma_f32_16x16x32_bf16(ah1, bl0, a10, 0, 0, 0);
    a11 = __builtin_amdgcn_mfma_f32_16x16x32_bf16(ah1, bl1, a11, 0, 0, 0);
    a00 = __builtin_amdgcn_mfma_f32_16x16x32_bf16(al0, bh0, a00, 0, 0, 0);
    a01 = __builtin_amdgcn_mfma_f32_16x16x32_bf16(al0, bh1, a01, 0, 0, 0);
    a10 = __builtin_amdgcn_mfma_f32_16x16x32_bf16(al1, bh0, a10, 0, 0, 0);
    a11 = __builtin_amdgcn_mfma_f32_16x16x32_bf16(al1, bh1, a11, 0, 0, 0);
  }
  float* pp = part + (size_t)(ks*NCAM + n)*FCc*PIX;
  int ocb = oc0 + ocr + ((lane >> 4) << 2);
  int pxb = px0 + pxr + (lane & 15);
  #pragma unroll
  for (int i = 0; i < 4; ++i) {
    pp[(size_t)(ocb + i)*PIX + pxb]           = a00[i];
    pp[(size_t)(ocb + i)*PIX + pxb + 16]      = a01[i];
    pp[(size_t)(ocb + 16 + i)*PIX + pxb]      = a10[i];
    pp[(size_t)(ocb + 16 + i)*PIX + pxb + 16] = a11[i];
  }
}

// bf16x3 MFMA GEMM for conv3 (1x1, K=128, bias fused, direct X3 write).
__global__ __launch_bounds__(256) void k_gemm_mfma3(
    const float* __restrict__ in, const float* ws,
    const float* __restrict__ bias, float* __restrict__ outbuf)
{
  __shared__ int alds[2][64*LROW];
  __shared__ int blds[2][64*LROW];
  int tid = threadIdx.x;
  int px0 = blockIdx.x * 64;
  int oc0 = blockIdx.y * 64;
  int n = blockIdx.z;
  const unsigned short* whi = (const unsigned short*)(ws + OFF_WT3);
  const unsigned short* wlo = whi + 24576;
  const float* inn = in + (size_t)n*FCc*PIX;
  int wv = tid >> 6, lane = tid & 63;
  int a_oc = tid >> 2, a_kq = tid & 3;
  int b_px = tid & 63, b_kq = tid >> 6;
  int p = px0 + b_px;

  i32x4 pa_h, pa_l; float bvv[8];
  auto issueA = [&](int s) {
    size_t gi = (size_t)(oc0 + a_oc)*128 + (s*32 + a_kq*8);
    pa_h = *(const i32x4*)(whi + gi);
    pa_l = *(const i32x4*)(wlo + gi);
  };
  auto issueB = [&](int s) {
    #pragma unroll
    for (int j = 0; j < 8; ++j) {
      int ic = s*32 + b_kq*8 + j;
      bvv[j] = inn[(size_t)ic*PIX + p];
    }
  };

  f32x4 a00 = {0.f,0.f,0.f,0.f}, a01 = a00, a10 = a00, a11 = a00;
  int ocr = (wv >> 1) * 32, pxr = (wv & 1) * 32;
  int dq = (lane >> 4) * 4;
  int rA0 = (ocr + (lane & 15)) * LROW + dq;
  int rA1 = rA0 + 16*LROW;
  int rB0 = (pxr + (lane & 15)) * LROW + dq;
  int rB1 = rB0 + 16*LROW;
  int aw = a_oc*LROW + a_kq*4;
  int bw = b_px*LROW + b_kq*4;

  issueA(0); issueB(0);
  for (int s = 0; s < 4; ++s) {
    __syncthreads();
    *(i32x4*)&alds[0][aw] = pa_h;
    *(i32x4*)&alds[1][aw] = pa_l;
    {
      i32x4 vh, vl;
      int th[8], tl[8];
      #pragma unroll
      for (int j = 0; j < 8; ++j) {
        unsigned short h = f2bf(bvv[j]);
        th[j] = h; tl[j] = f2bf(bvv[j] - bf2f(h));
      }
      vh.x = th[0]|(th[1]<<16); vh.y = th[2]|(th[3]<<16);
      vh.z = th[4]|(th[5]<<16); vh.w = th[6]|(th[7]<<16);
      vl.x = tl[0]|(tl[1]<<16); vl.y = tl[2]|(tl[3]<<16);
      vl.z = tl[4]|(tl[5]<<16); vl.w = tl[6]|(tl[7]<<16);
      *(i32x4*)&blds[0][bw] = vh;
      *(i32x4*)&blds[1][bw] = vl;
    }
    __syncthreads();
    if (s < 3) { issueA(s+1); issueB(s+1); }
    bf16x8 ah0 = *(bf16x8*)&alds[0][rA0], ah1 = *(bf16x8*)&alds[0][rA1];
    bf16x8 al0 = *(bf16x8*)&alds[1][rA0], al1 = *(bf16x8*)&alds[1][rA1];
    bf16x8 bh0 = *(bf16x8*)&blds[0][rB0], bh1 = *(bf16x8*)&blds[0][rB1];
    bf16x8 bl0 = *(bf16x8*)&blds[1][rB0], bl1 = *(bf16x8*)&blds[1][rB1];
    a00 = __builtin_amdgcn_mfma_f32_16x16x32_bf16(ah0, bh0, a00, 0, 0, 0);
    a01 = __builtin_amdgcn_mfma_f32_16x16x32_bf16(ah0, bh1, a01, 0, 0, 0);
    a10 = __builtin_amdgcn_mfma_f32_16x16x32_bf16(ah1, bh0, a10, 0, 0, 0);
    a11 = __builtin_amdgcn_mfma_f32_16x16x32_bf16(ah1, bh1, a11, 0, 0, 0);
    a00 = __builtin_amdgcn_mfma_f32_16x16x32_bf16(ah0, bl0, a00, 0, 0, 0);
    a01 = __builtin_amdgcn_mfma_f32_16x16x32_bf16(ah0, bl1, a01, 0, 0, 0);
    a10 = __builtin_amdgcn_mfma_f32_16x16x32_bf16(ah1, bl0, a10, 0, 0, 0);
    a11 = __builtin_amdgcn_mfma_f32_16x16x32_bf16(ah1, bl1, a11, 0, 0, 0);
    a00 = __builtin_amdgcn_mfma_f32_16x16x32_bf16(al0, bh0, a00, 0, 0, 0);
    a01 = __builtin_amdgcn_mfma_f32_16x16x32_bf16(al0, bh1, a01, 0, 0, 0);
    a10 = __builtin_amdgcn_mfma_f32_16x16x32_bf16(al1, bh0, a10, 0, 0, 0);
    a11 = __builtin_amdgcn_mfma_f32_16x16x32_bf16(al1, bh1, a11, 0, 0, 0);
  }
  int ocb = oc0 + ocr + ((lane >> 4) << 2);
  int pxb = px0 + pxr + (lane & 15);
  #pragma unroll
  for (int i = 0; i < 4; ++i) {
    int o0 = ocb + i, o1 = ocb + 16 + i;
    if (o0 < C3) {
      float b = bias[o0];
      outbuf[(size_t)(n*C3 + o0)*PIX + pxb]      = a00[i] + b;
      outbuf[(size_t)(n*C3 + o0)*PIX + pxb + 16] = a01[i] + b;
    }
    if (o1 < C3) {
      float b = bias[o1];
      outbuf[(size_t)(n*C3 + o1)*PIX + pxb]      = a10[i] + b;
      outbuf[(size_t)(n*C3 + o1)*PIX + pxb + 16] = a11[i] + b;
    }
  }
}

__global__ void k_epi_bn(const float* __restrict__ part, const float* __restrict__ cb,
                         const float* __restrict__ g, const float* __restrict__ be,
                         const float* __restrict__ mn, const float* __restrict__ vr,
                         float* __restrict__ out, int KSPLIT)
{
  int idx = blockIdx.x*256 + threadIdx.x;
  if (idx >= NCAM*FCc*176) return;
  int px4 = idx % 176;
  int t = idx / 176;
  int oc = t % FCc;
  int n = t / FCc;
  float4 s = {0.f,0.f,0.f,0.f};
  for (int ks = 0; ks < KSPLIT; ++ks) {
    const float4* p = (const float4*)(part + (size_t)((ks*NCAM+n)*FCc + oc)*PIX);
    float4 v = p[px4];
    s.x += v.x; s.y += v.y; s.z += v.z; s.w += v.w;
  }
  float inv = g[oc] * rsqrtf(vr[oc] + 1e-3f);
  float sh = (cb[oc] - mn[oc]) * inv + be[oc];
  float4 o;
  o.x = fmaxf(s.x*inv + sh, 0.f);
  o.y = fmaxf(s.y*inv + sh, 0.f);
  o.z = fmaxf(s.z*inv + sh, 0.f);
  o.w = fmaxf(s.w*inv + sh, 0.f);
  ((float4*)(out + (size_t)(n*FCc + oc)*PIX))[px4] = o;
}

__global__ void k_moments(float* __restrict__ ws) {
  int wid  = (blockIdx.x * 256 + threadIdx.x) >> 6;
  int lane = threadIdx.x & 63;
  int n = wid / PIX, hw = wid % PIX;
  const float* x3 = ws + OFF_X3 + (size_t)n*C3*PIX + hw;
  float logit = (lane < DB) ? x3[(size_t)lane*PIX] : -1e30f;
  float mx = logit;
  for (int off = 1; off < 64; off <<= 1) mx = fmaxf(mx, __shfl_xor(mx, off));
  float e = (lane < DB) ? expf(logit - mx) : 0.f;
  float s = e;
  for (int off = 1; off < 64; off <<= 1) s += __shfl_xor(s, off);
  float p = e / s;
  float gx = 0.f, gy = 0.f;
  if (lane < DB) {
    float2 g2 = ((const float2*)(ws + OFF_GEO))[(size_t)(n*DB + lane)*PIX + hw];
    gx = g2.x; gy = g2.y;
  }
  float sx = p*gx;
  for (int off = 1; off < 64; off <<= 1) sx += __shfl_xor(sx, off);
  float sy = p*gy;
  for (int off = 1; off < 64; off <<= 1) sy += __shfl_xor(sy, off);
  float dx = gx - sx, dy = gy - sy;
  float c00 = p*dx*dx, c01 = p*dx*dy, c11 = p*dy*dy;
  for (int off = 1; off < 64; off <<= 1) c00 += __shfl_xor(c00, off);
  for (int off = 1; off < 64; off <<= 1) c01 += __shfl_xor(c01, off);
  for (int off = 1; off < 64; off <<= 1) c11 += __shfl_xor(c11, off);
  float opl = x3[(size_t)DB*PIX];
  float opac = 1.f / (1.f + expf(-opl));
  float a = c11*(1.f/9.f) + 0.3f;
  float b = c01*(1.f/9.f);
  float c = c00*(1.f/9.f) + 0.3f;
  float py = 50.f - sy;
  float px = 50.f - sx;
  float det = a*c - b*b;
  float op = (opac > 0.05f) ? opac : 0.f;
  float invd = 1.f;
  if (det > 0.f) invd = 1.f/det; else op = 0.f;
  if (lane == 0) {
    float lop = (op > 0.f) ? logf(op) : -1e30f;   // log-space opacity
    ((float4*)(ws + OFF_PRM))[wid]  = make_float4(py, px, -0.5f*c*invd, -0.5f*a*invd);
    ((float2*)(ws + OFF_PRM2))[wid] = make_float2(b*invd, lop);
  }
  float* ft = ws + OFF_FEATT + (size_t)wid*128;
  ft[lane]      = x3[(size_t)(DB + 1 + lane)*PIX];
  ft[lane + 64] = x3[(size_t)(DB + 1 + lane + 64)*PIX];
}

template<int CTRL, int RMASK>
__device__ __forceinline__ float dpp_mul(float v) {
  int t = __builtin_amdgcn_update_dpp(0x3f800000, __float_as_int(v), CTRL, RMASK, 0xF, false);
  return v * __int_as_float(t);
}

// Split-K raster (R14 measured-best config): block = 8 pixels x 1 split of
// 1408 gaussians (22 groups), single 33.8KB LDS stage, log-reject + DPP scan
// + 8-wide batched f32 feature gather. Partials written as PACKED BF16
// (uint = 2 channels): halves SF write/read traffic; error ~2^-9*|F|.
__global__ __launch_bounds__(512) void k_raster(const float* __restrict__ ws,
                                                float* __restrict__ wsout) {
  __shared__ float4 s4[SG];
  __shared__ float2 s2[SG];
  int lane = threadIdx.x & 63, wv = threadIdx.x >> 6;
  int split = blockIdx.x / 1250;
  int pxb   = blockIdx.x % 1250;
  int pix = pxb * 8 + wv;
  float yi = (float)(pix / 100), xi = (float)(pix % 100);
  int gbase = split * SG;
  const float4* prm4 = (const float4*)(ws + OFF_PRM) + gbase;
  const float2* prm2 = (const float2*)(ws + OFF_PRM2) + gbase;
  const float2* ft = (const float2*)(ws + OFF_FEATT);
  for (int i = threadIdx.x; i < SG; i += 512) {
    s4[i] = prm4[i];
    s2[i] = prm2[i];
  }
  __syncthreads();
  float T = 1.f, ax = 0.f, ay = 0.f;
  for (int gl = 0; gl < SG; gl += 64) {
    float4 c4 = s4[gl + lane];
    float2 c2 = s2[gl + lane];
    float dyv = c4.x - yi, dxv = c4.y - xi;
    float pw = c4.z*dyv*dyv + c4.w*dxv*dxv + c2.x*dyv*dxv;
    float t  = pw + c2.y;                       // pw + log(op)
    bool hit = (t >= TH_LOG);
    unsigned long long m0 = __ballot(hit);
    if (m0) {
      float alpha = __expf(fminf(t, c2.y));     // op*exp(min(pw,0))
      alpha = fminf(alpha, 0.99f);
      alpha = hit ? alpha : 0.f;
      float P = 1.f - alpha;
      P = dpp_mul<0x111, 0xF>(P);
      P = dpp_mul<0x112, 0xF>(P);
      P = dpp_mul<0x114, 0xF>(P);
      P = dpp_mul<0x118, 0xF>(P);
      P = dpp_mul<0x142, 0xA>(P);
      P = dpp_mul<0x143, 0xC>(P);
      float E = __int_as_float(__builtin_amdgcn_update_dpp(
                  0x3f800000, __float_as_int(P), 0x138, 0xF, 0xF, false));
      float w = alpha * T * E;
      T *= __int_as_float(__builtin_amdgcn_readlane(__float_as_int(P), 63));
      unsigned long long mask = __ballot(w > 1e-9f);
      int g0 = gbase + gl;
      while (mask) {
        int jj[8];
        #pragma unroll
        for (int b = 0; b < 8; ++b) {
          if (mask) { jj[b] = __builtin_ctzll(mask); mask &= mask - 1ull; }
          else jj[b] = -1;
        }
        float2 fb[8]; float wb[8];
        #pragma unroll
        for (int b = 0; b < 8; ++b) {
          int j = (jj[b] >= 0) ? jj[b] : jj[0];
          fb[b] = ft[(size_t)(g0 + j)*64 + lane];
          wb[b] = (jj[b] >= 0)
            ? __int_as_float(__builtin_amdgcn_readlane(__float_as_int(w), jj[b]))
            : 0.f;
        }
        #pragma unroll
        for (int b = 0; b < 8; ++b) { ax += wb[b]*fb[b].x; ay += wb[b]*fb[b].y; }
      }
      if (T < 1e-7f) break;                     // local exit (error < 1e-7)
    }
  }
  unsigned* sfu = (unsigned*)(wsout + OFF_SF);
  sfu[((size_t)split*BEVN + pix)*64 + lane] =
      (unsigned)f2bf(ax) | ((unsigned)f2bf(ay) << 16);
  if (lane == 0) (wsout + OFF_SP)[split*BEVN + pix] = T;
}

// ordered combine: F = F0 + T0*F1 + T0*T1*F2 (packed bf16 partials)
__global__ __launch_bounds__(512) void k_combine(const float* __restrict__ ws,
                                                 float* __restrict__ out) {
  int lane = threadIdx.x & 63, wv = threadIdx.x >> 6;
  int pix = blockIdx.x * 8 + wv;
  const float* sp = ws + OFF_SP;
  float P0 = sp[pix], P1 = sp[BEVN + pix];
  const unsigned* sfu = (const unsigned*)(ws + OFF_SF);
  unsigned u0 = sfu[(size_t)pix*64 + lane];
  unsigned u1 = sfu[((size_t)BEVN + pix)*64 + lane];
  unsigned u2 = sfu[((size_t)2*BEVN + pix)*64 + lane];
  float w1 = P0, w2 = P0*P1;
  float ox = bf2f((unsigned short)(u0 & 0xffff))
           + w1*bf2f((unsigned short)(u1 & 0xffff))
           + w2*bf2f((unsigned short)(u2 & 0xffff));
  float oy = bf2f((unsigned short)(u0 >> 16))
           + w1*bf2f((unsigned short)(u1 >> 16))
           + w2*bf2f((unsigned short)(u2 >> 16));
  out[(size_t)(2*lane)*BEVN + pix]   = ox;
  out[(size_t)(2*lane+1)*BEVN + pix] = oy;
}

extern "C" void kernel_launch(void* const* d_in, const int* in_sizes, int n_in,
                              void* d_out, int out_size, void* d_ws, size_t ws_size,
                              hipStream_t stream) {
  const float* rot        = (const float*)d_in[0];
  const float* trans      = (const float*)d_in[1];
  const float* intr       = (const float*)d_in[2];
  const float* post_rot   = (const float*)d_in[3];
  const float* post_trans = (const float*)d_in[4];
  const float* img        = (const float*)d_in[5];
  const float* w1  = (const float*)d_in[6];
  const float* b1  = (const float*)d_in[7];
  const float* g1  = (const float*)d_in[8];
  const float* be1 = (const float*)d_in[9];
  const float* m1  = (const float*)d_in[10];
  const float* v1  = (const float*)d_in[11];
  const float* w2  = (const float*)d_in[12];
  const float* b2  = (const float*)d_in[13];
  const float* g2  = (const float*)d_in[14];
  const float* be2 = (const float*)d_in[15];
  const float* m2  = (const float*)d_in[16];
  const float* v2  = (const float*)d_in[17];
  const float* w3  = (const float*)d_in[18];
  const float* b3  = (const float*)d_in[19];
  float* ws  = (float*)d_ws;
  float* out = (float*)d_out;

  k_prep<<<1368, 256, 0, stream>>>(rot, intr, post_rot, trans, post_trans,
                                   w1, w2, w3, ws);

  // conv1: bf16x3 MFMA, K=1152, KSPLIT=4
  k_gemm_mfma<<<dim3(11,2,24), 256, 0, stream>>>(img, ws, ws+OFF_PART, OFF_WT1);
  k_epi_bn<<<528, 256, 0, stream>>>(ws+OFF_PART, b1, g1, be1, m1, v1, ws+OFF_X1, 4);
  // conv2
  k_gemm_mfma<<<dim3(11,2,24), 256, 0, stream>>>(ws+OFF_X1, ws, ws+OFF_PART, OFF_WT2);
  k_epi_bn<<<528, 256, 0, stream>>>(ws+OFF_PART, b2, g2, be2, m2, v2, ws+OFF_X2, 4);
  // conv3: 1x1, K=128, bf16x3 MFMA, bias fused, direct X3 write
  k_gemm_mfma3<<<dim3(11,3,6), 256, 0, stream>>>(ws+OFF_X2, ws, b3, ws+OFF_X3);

  k_moments<<<1056, 256, 0, stream>>>(ws);
  k_raster<<<3750, 512, 0, stream>>>(ws, ws);
  k_combine<<<1250, 512, 0, stream>>>(ws, out);
}

// Round 21
// 118.355 us; speedup vs baseline: 1.2016x; 1.0121x over previous
//
#include <hip/hip_runtime.h>
#include <math.h>

#define NCAM 6
#define FHh 16
#define FWw 44
#define PIX 704            // FHh*FWw
#define FCc 128
#define DB 48
#define C3 177             // DB + 1 + 128
#define KCONV 1152         // FCc*9
#define NG 4224            // NCAM*PIX
#define BEVN 10000
#define NSPLIT 3
#define SG 1408            // gaussians per split (22 groups of 64)
#define TH_LOG (-5.5412635f)   // -ln(255): alpha>=1/255  <=>  pw+lop >= TH_LOG

// ---- ws layout (float offsets) ----
#define OFF_WT1    0                           // bf16 hi/lo ushorts (147456 floats)
#define OFF_WT2    147456
#define OFF_WT3    294912                      // bf16 hi/lo [192][128] (24576 floats)
#define OFF_GEO    319488                      // [6*48*704][2]
#define OFF_X1     724992                      // [6][128][704]
#define OFF_X2     1265664
#define OFF_X3     1806336                     // [6][177][704]
#define OFF_PART   2553984                     // [4][6][128][704] conv partials
#define OFF_PRM    4716672                     // float4 [NG]: py,px,qc,qa
#define OFF_PRM2   4733568                     // float2 [NG]: qb,lop
#define OFF_FEATT  4742016                     // [NG][128] f32
#define OFF_SF     0                           // [NSPLIT][BEVN][64] uints (packed bf16 partials)
#define OFF_SP     3840000                     // [NSPLIT][BEVN] local transmittance
// end = 5,282,688 floats = 21.1 MiB

typedef __attribute__((ext_vector_type(8))) short bf16x8;
typedef __attribute__((ext_vector_type(4))) float f32x4;
typedef __attribute__((ext_vector_type(4))) int i32x4;

__device__ __forceinline__ unsigned short f2bf(float x) {
  unsigned u = __float_as_uint(x);
  return (unsigned short)((u + 0x7FFF + ((u >> 16) & 1)) >> 16);
}
__device__ __forceinline__ float bf2f(unsigned short h) {
  return __uint_as_float(((unsigned)h) << 16);
}

__device__ __forceinline__ void inv3(const float* A, float* I) {
  float a=A[0],b=A[1],c=A[2],d=A[3],e=A[4],f=A[5],g=A[6],h=A[7],i=A[8];
  float c0 = e*i - f*h, c1 = f*g - d*i, c2 = d*h - e*g;
  float det = a*c0 + b*c1 + c*c2;
  float id = 1.f/det;
  I[0]=c0*id; I[1]=(c*h-b*i)*id; I[2]=(b*f-c*e)*id;
  I[3]=c1*id; I[4]=(a*i-c*g)*id; I[5]=(c*d-a*f)*id;
  I[6]=c2*id; I[7]=(b*g-a*h)*id; I[8]=(a*e-b*d)*id;
}

// fused: blocks [0,792) = geometry; [792, 1368) = weight transform
__global__ void k_prep(const float* __restrict__ rot, const float* __restrict__ intr,
                       const float* __restrict__ post_rot,
                       const float* __restrict__ trans, const float* __restrict__ post_trans,
                       const float* __restrict__ w1, const float* __restrict__ w2,
                       const float* __restrict__ w3, float* __restrict__ ws) {
  if (blockIdx.x < 792) {
    __shared__ float sm[NCAM][24];
    if (threadIdx.x < NCAM) {
      int n = threadIdx.x;
      float ip[9], ii[9];
      inv3(post_rot + n*9, ip);
      inv3(intr + n*9, ii);
      const float* R = rot + n*9;
      for (int j = 0; j < 9; ++j) sm[n][j] = ip[j];
      for (int r = 0; r < 3; ++r)
        for (int c = 0; c < 3; ++c) {
          float s = 0.f;
          for (int k = 0; k < 3; ++k) s += R[r*3+k]*ii[k*3+c];
          sm[n][9 + r*3 + c] = s;
        }
    }
    __syncthreads();
    int idx = blockIdx.x*256 + threadIdx.x;
    if (idx >= NCAM*DB*PIX) return;
    int n = idx / (DB*PIX);
    int rem = idx % (DB*PIX);
    int d = rem / PIX;
    int hw = rem % PIX;
    int h = hw / FWw, w = hw % FWw;
    float fx = w * (351.0f/43.0f);
    float fy = h * (127.0f/15.0f);
    float fz = 1.0f + (float)d;
    const float* pt = post_trans + n*3;
    float v0 = fx - pt[0], v1 = fy - pt[1], v2 = fz - pt[2];
    const float* m = sm[n];
    float x = m[0]*v0 + m[1]*v1 + m[2]*v2;
    float y = m[3]*v0 + m[4]*v1 + m[5]*v2;
    float z = m[6]*v0 + m[7]*v1 + m[8]*v2;
    float q0 = x*z, q1 = y*z, q2 = z;
    const float* c = m + 9;
    const float* t = trans + n*3;
    float gx = c[0]*q0 + c[1]*q1 + c[2]*q2 + t[0];
    float gy = c[3]*q0 + c[4]*q1 + c[5]*q2 + t[1];
    ((float2*)(ws + OFF_GEO))[idx] = make_float2(gx, gy);
  } else {
    int e = (blockIdx.x - 792)*256 + threadIdx.x;
    if (e < 147456) {
      float v1 = w1[e], v2 = w2[e];
      unsigned short h1 = f2bf(v1), h2 = f2bf(v2);
      unsigned short l1 = f2bf(v1 - bf2f(h1)), l2 = f2bf(v2 - bf2f(h2));
      unsigned short* wt1 = (unsigned short*)(ws + OFF_WT1);
      unsigned short* wt2 = (unsigned short*)(ws + OFF_WT2);
      wt1[e] = h1; wt1[147456 + e] = l1;
      wt2[e] = h2; wt2[147456 + e] = l2;
    }
    if (e < 192*128) {                   // conv3: [oc<192][k<128], zero-pad oc>=177
      int oc = e >> 7, k = e & 127;
      float v = (oc < C3) ? w3[oc*FCc + k] : 0.f;
      unsigned short h = f2bf(v);
      unsigned short* wt3 = (unsigned short*)(ws + OFF_WT3);
      wt3[e] = h; wt3[24576 + e] = f2bf(v - bf2f(h));
    }
  }
}

#define LROW 20   // dwords per LDS row: 32 bf16 = 16 dw + 4 pad

// bf16x3 MFMA im2col GEMM, 3x3 convs. Block 256 thr = 4 waves, 64oc x 64px,
// Kchunk 288 (9 steps of K=32). D = AhBh + AhBl + AlBh.
__global__ __launch_bounds__(256) void k_gemm_mfma(
    const float* __restrict__ in, const float* ws, float* __restrict__ part, int woff)
{
  __shared__ int alds[2][64*LROW];
  __shared__ int blds[2][64*LROW];
  int tid = threadIdx.x;
  int px0 = blockIdx.x * 64;
  int oc0 = blockIdx.y * 64;
  int z = blockIdx.z; int n = z >> 2, ks = z & 3;
  const unsigned short* whi = (const unsigned short*)(ws + woff);
  const unsigned short* wlo = whi + 147456;
  const float* inn = in + (size_t)n*FCc*PIX;
  int wv = tid >> 6, lane = tid & 63;
  int a_oc = tid >> 2, a_kq = tid & 3;
  int b_px = tid & 63, b_kq = tid >> 6;
  int p = px0 + b_px; int b_y = p / FWw, b_x = p - b_y*FWw;
  int k00 = ks * 288;

  i32x4 pa_h, pa_l; float bv[8];
  auto issueA = [&](int s) {
    size_t gi = (size_t)(oc0 + a_oc)*KCONV + (k00 + s*32 + a_kq*8);
    pa_h = *(const i32x4*)(whi + gi);
    pa_l = *(const i32x4*)(wlo + gi);
  };
  auto issueB = [&](int s) {
    #pragma unroll
    for (int j = 0; j < 8; ++j) {
      int k = k00 + s*32 + b_kq*8 + j;
      int ic = k / 9, tap = k - ic*9;
      int ky = tap / 3, kx = tap - ky*3;
      int yy = b_y + ky - 1, xx = b_x + kx - 1;
      float v = 0.f;
      if ((unsigned)yy < FHh && (unsigned)xx < FWw) v = inn[(size_t)ic*PIX + yy*FWw + xx];
      bv[j] = v;
    }
  };

  f32x4 a00 = {0.f,0.f,0.f,0.f}, a01 = a00, a10 = a00, a11 = a00;
  int ocr = (wv >> 1) * 32, pxr = (wv & 1) * 32;
  int dq = (lane >> 4) * 4;
  int rA0 = (ocr + (lane & 15)) * LROW + dq;
  int rA1 = rA0 + 16*LROW;
  int rB0 = (pxr + (lane & 15)) * LROW + dq;
  int rB1 = rB0 + 16*LROW;
  int aw = a_oc*LROW + a_kq*4;
  int bw = b_px*LROW + b_kq*4;

  issueA(0); issueB(0);
  for (int s = 0; s < 9; ++s) {
    __syncthreads();
    *(i32x4*)&alds[0][aw] = pa_h;
    *(i32x4*)&alds[1][aw] = pa_l;
    {
      i32x4 vh, vl;
      int th[8], tl[8];
      #pragma unroll
      for (int j = 0; j < 8; ++j) {
        unsigned short h = f2bf(bv[j]);
        th[j] = h; tl[j] = f2bf(bv[j] - bf2f(h));
      }
      vh.x = th[0]|(th[1]<<16); vh.y = th[2]|(th[3]<<16);
      vh.z = th[4]|(th[5]<<16); vh.w = th[6]|(th[7]<<16);
      vl.x = tl[0]|(tl[1]<<16); vl.y = tl[2]|(tl[3]<<16);
      vl.z = tl[4]|(tl[5]<<16); vl.w = tl[6]|(tl[7]<<16);
      *(i32x4*)&blds[0][bw] = vh;
      *(i32x4*)&blds[1][bw] = vl;
    }
    __syncthreads();
    if (s < 8) { issueA(s+1); issueB(s+1); }
    bf16x8 ah0 = *(bf16x8*)&alds[0][rA0], ah1 = *(bf16x8*)&alds[0][rA1];
    bf16x8 al0 = *(bf16x8*)&alds[1][rA0], al1 = *(bf16x8*)&alds[1][rA1];
    bf16x8 bh0 = *(bf16x8*)&blds[0][rB0], bh1 = *(bf16x8*)&blds[0][rB1];
    bf16x8 bl0 = *(bf16x8*)&blds[1][rB0], bl1 = *(bf16x8*)&blds[1][rB1];
    a00 = __builtin_amdgcn_mfma_f32_16x16x32_bf16(ah0, bh0, a00, 0, 0, 0);
    a01 = __builtin_amdgcn_mfma_f32_16x16x32_bf16(ah0, bh1, a01, 0, 0, 0);
    a10 = __builtin_amdgcn_mfma_f32_16x16x32_bf16(ah1, bh0, a10, 0, 0, 0);
    a11 = __builtin_amdgcn_mfma_f32_16x16x32_bf16(ah1, bh1, a11, 0, 0, 0);
    a00 = __builtin_amdgcn_mfma_f32_16x16x32_bf16(ah0, bl0, a00, 0, 0, 0);
    a01 = __builtin_amdgcn_mfma_f32_16x16x32_bf16(ah0, bl1, a01, 0, 0, 0);
    a10 = __builtin_amdgcn_mfma_f32_16x16x32_bf16(ah1, bl0, a10, 0, 0, 0);
    a11 = __builtin_amdgcn_mfma_f32_16x16x32_bf16(ah1, bl1, a11, 0, 0, 0);
    a00 = __builtin_amdgcn_mfma_f32_16x16x32_bf16(al0, bh0, a00, 0, 0, 0);
    a01 = __builtin_amdgcn_mfma_f32_16x16x32_bf16(al0, bh1, a01, 0, 0, 0);
    a10 = __builtin_amdgcn_mfma_f32_16x16x32_bf16(al1, bh0, a10, 0, 0, 0);
    a11 = __builtin_amdgcn_mfma_f32_16x16x32_bf16(al1, bh1, a11, 0, 0, 0);
  }
  float* pp = part + (size_t)(ks*NCAM + n)*FCc*PIX;
  int ocb = oc0 + ocr + ((lane >> 4) << 2);
  int pxb = px0 + pxr + (lane & 15);
  #pragma unroll
  for (int i = 0; i < 4; ++i) {
    pp[(size_t)(ocb + i)*PIX + pxb]           = a00[i];
    pp[(size_t)(ocb + i)*PIX + pxb + 16]      = a01[i];
    pp[(size_t)(ocb + 16 + i)*PIX + pxb]      = a10[i];
    pp[(size_t)(ocb + 16 + i)*PIX + pxb + 16] = a11[i];
  }
}

// bf16x3 MFMA GEMM for conv3 (1x1, K=128, bias fused, direct X3 write).
__global__ __launch_bounds__(256) void k_gemm_mfma3(
    const float* __restrict__ in, const float* ws,
    const float* __restrict__ bias, float* __restrict__ outbuf)
{
  __shared__ int alds[2][64*LROW];
  __shared__ int blds[2][64*LROW];
  int tid = threadIdx.x;
  int px0 = blockIdx.x * 64;
  int oc0 = blockIdx.y * 64;
  int n = blockIdx.z;
  const unsigned short* whi = (const unsigned short*)(ws + OFF_WT3);
  const unsigned short* wlo = whi + 24576;
  const float* inn = in + (size_t)n*FCc*PIX;
  int wv = tid >> 6, lane = tid & 63;
  int a_oc = tid >> 2, a_kq = tid & 3;
  int b_px = tid & 63, b_kq = tid >> 6;
  int p = px0 + b_px;

  i32x4 pa_h, pa_l; float bvv[8];
  auto issueA = [&](int s) {
    size_t gi = (size_t)(oc0 + a_oc)*128 + (s*32 + a_kq*8);
    pa_h = *(const i32x4*)(whi + gi);
    pa_l = *(const i32x4*)(wlo + gi);
  };
  auto issueB = [&](int s) {
    #pragma unroll
    for (int j = 0; j < 8; ++j) {
      int ic = s*32 + b_kq*8 + j;
      bvv[j] = inn[(size_t)ic*PIX + p];
    }
  };

  f32x4 a00 = {0.f,0.f,0.f,0.f}, a01 = a00, a10 = a00, a11 = a00;
  int ocr = (wv >> 1) * 32, pxr = (wv & 1) * 32;
  int dq = (lane >> 4) * 4;
  int rA0 = (ocr + (lane & 15)) * LROW + dq;
  int rA1 = rA0 + 16*LROW;
  int rB0 = (pxr + (lane & 15)) * LROW + dq;
  int rB1 = rB0 + 16*LROW;
  int aw = a_oc*LROW + a_kq*4;
  int bw = b_px*LROW + b_kq*4;

  issueA(0); issueB(0);
  for (int s = 0; s < 4; ++s) {
    __syncthreads();
    *(i32x4*)&alds[0][aw] = pa_h;
    *(i32x4*)&alds[1][aw] = pa_l;
    {
      i32x4 vh, vl;
      int th[8], tl[8];
      #pragma unroll
      for (int j = 0; j < 8; ++j) {
        unsigned short h = f2bf(bvv[j]);
        th[j] = h; tl[j] = f2bf(bvv[j] - bf2f(h));
      }
      vh.x = th[0]|(th[1]<<16); vh.y = th[2]|(th[3]<<16);
      vh.z = th[4]|(th[5]<<16); vh.w = th[6]|(th[7]<<16);
      vl.x = tl[0]|(tl[1]<<16); vl.y = tl[2]|(tl[3]<<16);
      vl.z = tl[4]|(tl[5]<<16); vl.w = tl[6]|(tl[7]<<16);
      *(i32x4*)&blds[0][bw] = vh;
      *(i32x4*)&blds[1][bw] = vl;
    }
    __syncthreads();
    if (s < 3) { issueA(s+1); issueB(s+1); }
    bf16x8 ah0 = *(bf16x8*)&alds[0][rA0], ah1 = *(bf16x8*)&alds[0][rA1];
    bf16x8 al0 = *(bf16x8*)&alds[1][rA0], al1 = *(bf16x8*)&alds[1][rA1];
    bf16x8 bh0 = *(bf16x8*)&blds[0][rB0], bh1 = *(bf16x8*)&blds[0][rB1];
    bf16x8 bl0 = *(bf16x8*)&blds[1][rB0], bl1 = *(bf16x8*)&blds[1][rB1];
    a00 = __builtin_amdgcn_mfma_f32_16x16x32_bf16(ah0, bh0, a00, 0, 0, 0);
    a01 = __builtin_amdgcn_mfma_f32_16x16x32_bf16(ah0, bh1, a01, 0, 0, 0);
    a10 = __builtin_amdgcn_mfma_f32_16x16x32_bf16(ah1, bh0, a10, 0, 0, 0);
    a11 = __builtin_amdgcn_mfma_f32_16x16x32_bf16(ah1, bh1, a11, 0, 0, 0);
    a00 = __builtin_amdgcn_mfma_f32_16x16x32_bf16(ah0, bl0, a00, 0, 0, 0);
    a01 = __builtin_amdgcn_mfma_f32_16x16x32_bf16(ah0, bl1, a01, 0, 0, 0);
    a10 = __builtin_amdgcn_mfma_f32_16x16x32_bf16(ah1, bl0, a10, 0, 0, 0);
    a11 = __builtin_amdgcn_mfma_f32_16x16x32_bf16(ah1, bl1, a11, 0, 0, 0);
    a00 = __builtin_amdgcn_mfma_f32_16x16x32_bf16(al0, bh0, a00, 0, 0, 0);
    a01 = __builtin_amdgcn_mfma_f32_16x16x32_bf16(al0, bh1, a01, 0, 0, 0);
    a10 = __builtin_amdgcn_mfma_f32_16x16x32_bf16(al1, bh0, a10, 0, 0, 0);
    a11 = __builtin_amdgcn_mfma_f32_16x16x32_bf16(al1, bh1, a11, 0, 0, 0);
  }
  int ocb = oc0 + ocr + ((lane >> 4) << 2);
  int pxb = px0 + pxr + (lane & 15);
  #pragma unroll
  for (int i = 0; i < 4; ++i) {
    int o0 = ocb + i, o1 = ocb + 16 + i;
    if (o0 < C3) {
      float b = bias[o0];
      outbuf[(size_t)(n*C3 + o0)*PIX + pxb]      = a00[i] + b;
      outbuf[(size_t)(n*C3 + o0)*PIX + pxb + 16] = a01[i] + b;
    }
    if (o1 < C3) {
      float b = bias[o1];
      outbuf[(size_t)(n*C3 + o1)*PIX + pxb]      = a10[i] + b;
      outbuf[(size_t)(n*C3 + o1)*PIX + pxb + 16] = a11[i] + b;
    }
  }
}

__global__ void k_epi_bn(const float* __restrict__ part, const float* __restrict__ cb,
                         const float* __restrict__ g, const float* __restrict__ be,
                         const float* __restrict__ mn, const float* __restrict__ vr,
                         float* __restrict__ out, int KSPLIT)
{
  int idx = blockIdx.x*256 + threadIdx.x;
  if (idx >= NCAM*FCc*176) return;
  int px4 = idx % 176;
  int t = idx / 176;
  int oc = t % FCc;
  int n = t / FCc;
  float4 s = {0.f,0.f,0.f,0.f};
  for (int ks = 0; ks < KSPLIT; ++ks) {
    const float4* p = (const float4*)(part + (size_t)((ks*NCAM+n)*FCc + oc)*PIX);
    float4 v = p[px4];
    s.x += v.x; s.y += v.y; s.z += v.z; s.w += v.w;
  }
  float inv = g[oc] * rsqrtf(vr[oc] + 1e-3f);
  float sh = (cb[oc] - mn[oc]) * inv + be[oc];
  float4 o;
  o.x = fmaxf(s.x*inv + sh, 0.f);
  o.y = fmaxf(s.y*inv + sh, 0.f);
  o.z = fmaxf(s.z*inv + sh, 0.f);
  o.w = fmaxf(s.w*inv + sh, 0.f);
  ((float4*)(out + (size_t)(n*FCc + oc)*PIX))[px4] = o;
}

// Coalesced moments: block = 64 hw x 4 waves (lane = hw). Depth split 12/wave,
// LDS tree reduce for softmax stats (3 passes, exact same math as before);
// per-hw params by wave 0; features via 64x65 LDS tile transpose (+1 pad).
// All global accesses coalesced (old version: every load was a 64-line gather).
__global__ __launch_bounds__(256) void k_moments(float* __restrict__ ws) {
  __shared__ float r0[4][64], r1[4][64], r2[4][64];
  __shared__ float tile[64][65];
  int tid = threadIdx.x;
  int w = tid >> 6, l = tid & 63;
  int n = blockIdx.x / 11, hw0 = (blockIdx.x % 11) * 64;
  int hw = hw0 + l;
  const float* x3 = ws + OFF_X3 + (size_t)n*C3*PIX;
  const float2* geo = (const float2*)(ws + OFF_GEO);
  float le[12], gxr[12], gyr[12];
  // pass 1: per-wave partial max over its 12 depths (coalesced in hw)
  float pm = -1e30f;
  #pragma unroll
  for (int j = 0; j < 12; ++j) {
    le[j] = x3[(size_t)(w*12 + j)*PIX + hw];
    pm = fmaxf(pm, le[j]);
  }
  r0[w][l] = pm;
  __syncthreads();
  float mx = fmaxf(fmaxf(r0[0][l], r0[1][l]), fmaxf(r0[2][l], r0[3][l]));
  __syncthreads();
  // pass 2: e, partial {s, e*gx, e*gy}
  float s_p = 0.f, sx_p = 0.f, sy_p = 0.f;
  #pragma unroll
  for (int j = 0; j < 12; ++j) {
    float e = expf(le[j] - mx);
    le[j] = e;
    float2 g2 = geo[(size_t)(n*DB + w*12 + j)*PIX + hw];
    gxr[j] = g2.x; gyr[j] = g2.y;
    s_p += e; sx_p += e*g2.x; sy_p += e*g2.y;
  }
  r0[w][l] = s_p; r1[w][l] = sx_p; r2[w][l] = sy_p;
  __syncthreads();
  float s  = r0[0][l] + r0[1][l] + r0[2][l] + r0[3][l];
  float sx = (r1[0][l] + r1[1][l] + r1[2][l] + r1[3][l]) / s;
  float sy = (r2[0][l] + r2[1][l] + r2[2][l] + r2[3][l]) / s;
  __syncthreads();
  // pass 3: covariance partials with exact sx,sy
  float cxx = 0.f, cxy = 0.f, cyy = 0.f;
  #pragma unroll
  for (int j = 0; j < 12; ++j) {
    float dx = gxr[j] - sx, dy = gyr[j] - sy;
    cxx += le[j]*dx*dx; cxy += le[j]*dx*dy; cyy += le[j]*dy*dy;
  }
  r0[w][l] = cxx; r1[w][l] = cxy; r2[w][l] = cyy;
  __syncthreads();
  if (w == 0) {
    float c00 = (r0[0][l] + r0[1][l] + r0[2][l] + r0[3][l]) / s;
    float c01 = (r1[0][l] + r1[1][l] + r1[2][l] + r1[3][l]) / s;
    float c11 = (r2[0][l] + r2[1][l] + r2[2][l] + r2[3][l]) / s;
    float opl = x3[(size_t)DB*PIX + hw];
    float opac = 1.f / (1.f + expf(-opl));
    float a = c11*(1.f/9.f) + 0.3f;
    float b = c01*(1.f/9.f);
    float c = c00*(1.f/9.f) + 0.3f;
    float py = 50.f - sy;
    float px = 50.f - sx;
    float det = a*c - b*b;
    float op = (opac > 0.05f) ? opac : 0.f;
    float invd = 1.f;
    if (det > 0.f) invd = 1.f/det; else op = 0.f;
    float lop = (op > 0.f) ? logf(op) : -1e30f;
    int wid = n*PIX + hw;
    ((float4*)(ws + OFF_PRM))[wid]  = make_float4(py, px, -0.5f*c*invd, -0.5f*a*invd);
    ((float2*)(ws + OFF_PRM2))[wid] = make_float2(b*invd, lop);
  }
  // features: two 64-channel tile transposes through LDS
  float* ft = ws + OFF_FEATT;
  for (int half = 0; half < 2; ++half) {
    __syncthreads();
    int ch0 = half*64;
    #pragma unroll
    for (int r = 0; r < 16; ++r) {
      int ch = w*16 + r;
      tile[ch][l] = x3[(size_t)(DB + 1 + ch0 + ch)*PIX + hw];  // coalesced read
    }
    __syncthreads();
    #pragma unroll
    for (int k = 0; k < 16; ++k) {
      int h = w + 4*k;                                          // hw offset 0..63
      ft[(size_t)(n*PIX + hw0 + h)*128 + ch0 + l] = tile[l][h]; // coalesced write
    }
  }
}

template<int CTRL, int RMASK>
__device__ __forceinline__ float dpp_mul(float v) {
  int t = __builtin_amdgcn_update_dpp(0x3f800000, __float_as_int(v), CTRL, RMASK, 0xF, false);
  return v * __int_as_float(t);
}

// Split-K raster (R14/R20 measured-best): block = 8 pixels x 1 split of
// 1408 gaussians, single 33.8KB LDS stage, log-reject + DPP scan + 8-wide
// batched f32 feature gather. Partials written as packed bf16.
__global__ __launch_bounds__(512) void k_raster(const float* __restrict__ ws,
                                                float* __restrict__ wsout) {
  __shared__ float4 s4[SG];
  __shared__ float2 s2[SG];
  int lane = threadIdx.x & 63, wv = threadIdx.x >> 6;
  int split = blockIdx.x / 1250;
  int pxb   = blockIdx.x % 1250;
  int pix = pxb * 8 + wv;
  float yi = (float)(pix / 100), xi = (float)(pix % 100);
  int gbase = split * SG;
  const float4* prm4 = (const float4*)(ws + OFF_PRM) + gbase;
  const float2* prm2 = (const float2*)(ws + OFF_PRM2) + gbase;
  const float2* ft = (const float2*)(ws + OFF_FEATT);
  for (int i = threadIdx.x; i < SG; i += 512) {
    s4[i] = prm4[i];
    s2[i] = prm2[i];
  }
  __syncthreads();
  float T = 1.f, ax = 0.f, ay = 0.f;
  for (int gl = 0; gl < SG; gl += 64) {
    float4 c4 = s4[gl + lane];
    float2 c2 = s2[gl + lane];
    float dyv = c4.x - yi, dxv = c4.y - xi;
    float pw = c4.z*dyv*dyv + c4.w*dxv*dxv + c2.x*dyv*dxv;
    float t  = pw + c2.y;                       // pw + log(op)
    bool hit = (t >= TH_LOG);
    unsigned long long m0 = __ballot(hit);
    if (m0) {
      float alpha = __expf(fminf(t, c2.y));     // op*exp(min(pw,0))
      alpha = fminf(alpha, 0.99f);
      alpha = hit ? alpha : 0.f;
      float P = 1.f - alpha;
      P = dpp_mul<0x111, 0xF>(P);
      P = dpp_mul<0x112, 0xF>(P);
      P = dpp_mul<0x114, 0xF>(P);
      P = dpp_mul<0x118, 0xF>(P);
      P = dpp_mul<0x142, 0xA>(P);
      P = dpp_mul<0x143, 0xC>(P);
      float E = __int_as_float(__builtin_amdgcn_update_dpp(
                  0x3f800000, __float_as_int(P), 0x138, 0xF, 0xF, false));
      float w = alpha * T * E;
      T *= __int_as_float(__builtin_amdgcn_readlane(__float_as_int(P), 63));
      unsigned long long mask = __ballot(w > 1e-9f);
      int g0 = gbase + gl;
      while (mask) {
        int jj[8];
        #pragma unroll
        for (int b = 0; b < 8; ++b) {
          if (mask) { jj[b] = __builtin_ctzll(mask); mask &= mask - 1ull; }
          else jj[b] = -1;
        }
        float2 fb[8]; float wb[8];
        #pragma unroll
        for (int b = 0; b < 8; ++b) {
          int j = (jj[b] >= 0) ? jj[b] : jj[0];
          fb[b] = ft[(size_t)(g0 + j)*64 + lane];
          wb[b] = (jj[b] >= 0)
            ? __int_as_float(__builtin_amdgcn_readlane(__float_as_int(w), jj[b]))
            : 0.f;
        }
        #pragma unroll
        for (int b = 0; b < 8; ++b) { ax += wb[b]*fb[b].x; ay += wb[b]*fb[b].y; }
      }
      if (T < 1e-7f) break;                     // local exit (error < 1e-7)
    }
  }
  unsigned* sfu = (unsigned*)(wsout + OFF_SF);
  sfu[((size_t)split*BEVN + pix)*64 + lane] =
      (unsigned)f2bf(ax) | ((unsigned)f2bf(ay) << 16);
  if (lane == 0) (wsout + OFF_SP)[split*BEVN + pix] = T;
}

// ordered combine: F = F0 + T0*F1 + T0*T1*F2 (packed bf16 partials)
__global__ __launch_bounds__(512) void k_combine(const float* __restrict__ ws,
                                                 float* __restrict__ out) {
  int lane = threadIdx.x & 63, wv = threadIdx.x >> 6;
  int pix = blockIdx.x * 8 + wv;
  const float* sp = ws + OFF_SP;
  float P0 = sp[pix], P1 = sp[BEVN + pix];
  const unsigned* sfu = (const unsigned*)(ws + OFF_SF);
  unsigned u0 = sfu[(size_t)pix*64 + lane];
  unsigned u1 = sfu[((size_t)BEVN + pix)*64 + lane];
  unsigned u2 = sfu[((size_t)2*BEVN + pix)*64 + lane];
  float w1 = P0, w2 = P0*P1;
  float ox = bf2f((unsigned short)(u0 & 0xffff))
           + w1*bf2f((unsigned short)(u1 & 0xffff))
           + w2*bf2f((unsigned short)(u2 & 0xffff));
  float oy = bf2f((unsigned short)(u0 >> 16))
           + w1*bf2f((unsigned short)(u1 >> 16))
           + w2*bf2f((unsigned short)(u2 >> 16));
  out[(size_t)(2*lane)*BEVN + pix]   = ox;
  out[(size_t)(2*lane+1)*BEVN + pix] = oy;
}

extern "C" void kernel_launch(void* const* d_in, const int* in_sizes, int n_in,
                              void* d_out, int out_size, void* d_ws, size_t ws_size,
                              hipStream_t stream) {
  const float* rot        = (const float*)d_in[0];
  const float* trans      = (const float*)d_in[1];
  const float* intr       = (const float*)d_in[2];
  const float* post_rot   = (const float*)d_in[3];
  const float* post_trans = (const float*)d_in[4];
  const float* img        = (const float*)d_in[5];
  const float* w1  = (const float*)d_in[6];
  const float* b1  = (const float*)d_in[7];
  const float* g1  = (const float*)d_in[8];
  const float* be1 = (const float*)d_in[9];
  const float* m1  = (const float*)d_in[10];
  const float* v1  = (const float*)d_in[11];
  const float* w2  = (const float*)d_in[12];
  const float* b2  = (const float*)d_in[13];
  const float* g2  = (const float*)d_in[14];
  const float* be2 = (const float*)d_in[15];
  const float* m2  = (const float*)d_in[16];
  const float* v2  = (const float*)d_in[17];
  const float* w3  = (const float*)d_in[18];
  const float* b3  = (const float*)d_in[19];
  float* ws  = (float*)d_ws;
  float* out = (float*)d_out;

  k_prep<<<1368, 256, 0, stream>>>(rot, intr, post_rot, trans, post_trans,
                                   w1, w2, w3, ws);

  // conv1: bf16x3 MFMA, K=1152, KSPLIT=4
  k_gemm_mfma<<<dim3(11,2,24), 256, 0, stream>>>(img, ws, ws+OFF_PART, OFF_WT1);
  k_epi_bn<<<528, 256, 0, stream>>>(ws+OFF_PART, b1, g1, be1, m1, v1, ws+OFF_X1, 4);
  // conv2
  k_gemm_mfma<<<dim3(11,2,24), 256, 0, stream>>>(ws+OFF_X1, ws, ws+OFF_PART, OFF_WT2);
  k_epi_bn<<<528, 256, 0, stream>>>(ws+OFF_PART, b2, g2, be2, m2, v2, ws+OFF_X2, 4);
  // conv3: 1x1, K=128, bf16x3 MFMA, bias fused, direct X3 write
  k_gemm_mfma3<<<dim3(11,3,6), 256, 0, stream>>>(ws+OFF_X2, ws, b3, ws+OFF_X3);

  k_moments<<<66, 256, 0, stream>>>(ws);
  k_raster<<<3750, 512, 0, stream>>>(ws, ws);
  k_combine<<<1250, 512, 0, stream>>>(ws, out);
}

// Round 22
// 116.567 us; speedup vs baseline: 1.2200x; 1.0153x over previous
//
#include <hip/hip_runtime.h>
#include <math.h>

#define NCAM 6
#define FHh 16
#define FWw 44
#define PIX 704            // FHh*FWw
#define FCc 128
#define DB 48
#define C3 177             // DB + 1 + 128
#define KCONV 1152         // FCc*9
#define NG 4224            // NCAM*PIX
#define BEVN 10000
#define NSPLIT 6
#define SG 704             // gaussians per split (11 groups of 64)
#define TH_LOG (-5.5412635f)   // -ln(255): alpha>=1/255  <=>  pw+lop >= TH_LOG

// ---- ws layout (float offsets) ----
#define OFF_WT1    0                           // bf16 hi/lo ushorts (147456 floats)
#define OFF_WT2    147456
#define OFF_WT3    294912                      // bf16 hi/lo [192][128] (24576 floats)
#define OFF_GEO    319488                      // [6*48*704][2]
#define OFF_X1     724992                      // [6][128][704]
#define OFF_X2     1265664
#define OFF_X3     1806336                     // [6][177][704]
#define OFF_PART   2553984                     // [4][6][128][704] conv partials
#define OFF_PRM    4716672                     // float4 [NG]: py,px,qc,qa
#define OFF_PRM2   4733568                     // float2 [NG]: qb,lop
#define OFF_FEATT  4742016                     // [NG][128] f32
#define OFF_SF     0                           // [NSPLIT][BEVN][64] uints (packed bf16 partials)
#define OFF_SP     3840000                     // [NSPLIT][BEVN] local transmittance
// end = 5,282,688 floats = 21.1 MiB

typedef __attribute__((ext_vector_type(8))) short bf16x8;
typedef __attribute__((ext_vector_type(4))) float f32x4;
typedef __attribute__((ext_vector_type(4))) int i32x4;

__device__ __forceinline__ unsigned short f2bf(float x) {
  unsigned u = __float_as_uint(x);
  return (unsigned short)((u + 0x7FFF + ((u >> 16) & 1)) >> 16);
}
__device__ __forceinline__ float bf2f(unsigned short h) {
  return __uint_as_float(((unsigned)h) << 16);
}

__device__ __forceinline__ void inv3(const float* A, float* I) {
  float a=A[0],b=A[1],c=A[2],d=A[3],e=A[4],f=A[5],g=A[6],h=A[7],i=A[8];
  float c0 = e*i - f*h, c1 = f*g - d*i, c2 = d*h - e*g;
  float det = a*c0 + b*c1 + c*c2;
  float id = 1.f/det;
  I[0]=c0*id; I[1]=(c*h-b*i)*id; I[2]=(b*f-c*e)*id;
  I[3]=c1*id; I[4]=(a*i-c*g)*id; I[5]=(c*d-a*f)*id;
  I[6]=c2*id; I[7]=(b*g-a*h)*id; I[8]=(a*e-b*d)*id;
}

// fused: blocks [0,792) = geometry; [792, 1368) = weight transform
__global__ void k_prep(const float* __restrict__ rot, const float* __restrict__ intr,
                       const float* __restrict__ post_rot,
                       const float* __restrict__ trans, const float* __restrict__ post_trans,
                       const float* __restrict__ w1, const float* __restrict__ w2,
                       const float* __restrict__ w3, float* __restrict__ ws) {
  if (blockIdx.x < 792) {
    __shared__ float sm[NCAM][24];
    if (threadIdx.x < NCAM) {
      int n = threadIdx.x;
      float ip[9], ii[9];
      inv3(post_rot + n*9, ip);
      inv3(intr + n*9, ii);
      const float* R = rot + n*9;
      for (int j = 0; j < 9; ++j) sm[n][j] = ip[j];
      for (int r = 0; r < 3; ++r)
        for (int c = 0; c < 3; ++c) {
          float s = 0.f;
          for (int k = 0; k < 3; ++k) s += R[r*3+k]*ii[k*3+c];
          sm[n][9 + r*3 + c] = s;
        }
    }
    __syncthreads();
    int idx = blockIdx.x*256 + threadIdx.x;
    if (idx >= NCAM*DB*PIX) return;
    int n = idx / (DB*PIX);
    int rem = idx % (DB*PIX);
    int d = rem / PIX;
    int hw = rem % PIX;
    int h = hw / FWw, w = hw % FWw;
    float fx = w * (351.0f/43.0f);
    float fy = h * (127.0f/15.0f);
    float fz = 1.0f + (float)d;
    const float* pt = post_trans + n*3;
    float v0 = fx - pt[0], v1 = fy - pt[1], v2 = fz - pt[2];
    const float* m = sm[n];
    float x = m[0]*v0 + m[1]*v1 + m[2]*v2;
    float y = m[3]*v0 + m[4]*v1 + m[5]*v2;
    float z = m[6]*v0 + m[7]*v1 + m[8]*v2;
    float q0 = x*z, q1 = y*z, q2 = z;
    const float* c = m + 9;
    const float* t = trans + n*3;
    float gx = c[0]*q0 + c[1]*q1 + c[2]*q2 + t[0];
    float gy = c[3]*q0 + c[4]*q1 + c[5]*q2 + t[1];
    ((float2*)(ws + OFF_GEO))[idx] = make_float2(gx, gy);
  } else {
    int e = (blockIdx.x - 792)*256 + threadIdx.x;
    if (e < 147456) {
      float v1 = w1[e], v2 = w2[e];
      unsigned short h1 = f2bf(v1), h2 = f2bf(v2);
      unsigned short l1 = f2bf(v1 - bf2f(h1)), l2 = f2bf(v2 - bf2f(h2));
      unsigned short* wt1 = (unsigned short*)(ws + OFF_WT1);
      unsigned short* wt2 = (unsigned short*)(ws + OFF_WT2);
      wt1[e] = h1; wt1[147456 + e] = l1;
      wt2[e] = h2; wt2[147456 + e] = l2;
    }
    if (e < 192*128) {                   // conv3: [oc<192][k<128], zero-pad oc>=177
      int oc = e >> 7, k = e & 127;
      float v = (oc < C3) ? w3[oc*FCc + k] : 0.f;
      unsigned short h = f2bf(v);
      unsigned short* wt3 = (unsigned short*)(ws + OFF_WT3);
      wt3[e] = h; wt3[24576 + e] = f2bf(v - bf2f(h));
    }
  }
}

#define LROW 20   // dwords per LDS row: 32 bf16 = 16 dw + 4 pad

// bf16x3 MFMA im2col GEMM, 3x3 convs. Block 256 thr = 4 waves, 64oc x 64px,
// Kchunk 288 (9 steps of K=32). D = AhBh + AhBl + AlBh.
__global__ __launch_bounds__(256) void k_gemm_mfma(
    const float* __restrict__ in, const float* ws, float* __restrict__ part, int woff)
{
  __shared__ int alds[2][64*LROW];
  __shared__ int blds[2][64*LROW];
  int tid = threadIdx.x;
  int px0 = blockIdx.x * 64;
  int oc0 = blockIdx.y * 64;
  int z = blockIdx.z; int n = z >> 2, ks = z & 3;
  const unsigned short* whi = (const unsigned short*)(ws + woff);
  const unsigned short* wlo = whi + 147456;
  const float* inn = in + (size_t)n*FCc*PIX;
  int wv = tid >> 6, lane = tid & 63;
  int a_oc = tid >> 2, a_kq = tid & 3;
  int b_px = tid & 63, b_kq = tid >> 6;
  int p = px0 + b_px; int b_y = p / FWw, b_x = p - b_y*FWw;
  int k00 = ks * 288;

  i32x4 pa_h, pa_l; float bv[8];
  auto issueA = [&](int s) {
    size_t gi = (size_t)(oc0 + a_oc)*KCONV + (k00 + s*32 + a_kq*8);
    pa_h = *(const i32x4*)(whi + gi);
    pa_l = *(const i32x4*)(wlo + gi);
  };
  auto issueB = [&](int s) {
    #pragma unroll
    for (int j = 0; j < 8; ++j) {
      int k = k00 + s*32 + b_kq*8 + j;
      int ic = k / 9, tap = k - ic*9;
      int ky = tap / 3, kx = tap - ky*3;
      int yy = b_y + ky - 1, xx = b_x + kx - 1;
      float v = 0.f;
      if ((unsigned)yy < FHh && (unsigned)xx < FWw) v = inn[(size_t)ic*PIX + yy*FWw + xx];
      bv[j] = v;
    }
  };

  f32x4 a00 = {0.f,0.f,0.f,0.f}, a01 = a00, a10 = a00, a11 = a00;
  int ocr = (wv >> 1) * 32, pxr = (wv & 1) * 32;
  int dq = (lane >> 4) * 4;
  int rA0 = (ocr + (lane & 15)) * LROW + dq;
  int rA1 = rA0 + 16*LROW;
  int rB0 = (pxr + (lane & 15)) * LROW + dq;
  int rB1 = rB0 + 16*LROW;
  int aw = a_oc*LROW + a_kq*4;
  int bw = b_px*LROW + b_kq*4;

  issueA(0); issueB(0);
  for (int s = 0; s < 9; ++s) {
    __syncthreads();
    *(i32x4*)&alds[0][aw] = pa_h;
    *(i32x4*)&alds[1][aw] = pa_l;
    {
      i32x4 vh, vl;
      int th[8], tl[8];
      #pragma unroll
      for (int j = 0; j < 8; ++j) {
        unsigned short h = f2bf(bv[j]);
        th[j] = h; tl[j] = f2bf(bv[j] - bf2f(h));
      }
      vh.x = th[0]|(th[1]<<16); vh.y = th[2]|(th[3]<<16);
      vh.z = th[4]|(th[5]<<16); vh.w = th[6]|(th[7]<<16);
      vl.x = tl[0]|(tl[1]<<16); vl.y = tl[2]|(tl[3]<<16);
      vl.z = tl[4]|(tl[5]<<16); vl.w = tl[6]|(tl[7]<<16);
      *(i32x4*)&blds[0][bw] = vh;
      *(i32x4*)&blds[1][bw] = vl;
    }
    __syncthreads();
    if (s < 8) { issueA(s+1); issueB(s+1); }
    bf16x8 ah0 = *(bf16x8*)&alds[0][rA0], ah1 = *(bf16x8*)&alds[0][rA1];
    bf16x8 al0 = *(bf16x8*)&alds[1][rA0], al1 = *(bf16x8*)&alds[1][rA1];
    bf16x8 bh0 = *(bf16x8*)&blds[0][rB0], bh1 = *(bf16x8*)&blds[0][rB1];
    bf16x8 bl0 = *(bf16x8*)&blds[1][rB0], bl1 = *(bf16x8*)&blds[1][rB1];
    a00 = __builtin_amdgcn_mfma_f32_16x16x32_bf16(ah0, bh0, a00, 0, 0, 0);
    a01 = __builtin_amdgcn_mfma_f32_16x16x32_bf16(ah0, bh1, a01, 0, 0, 0);
    a10 = __builtin_amdgcn_mfma_f32_16x16x32_bf16(ah1, bh0, a10, 0, 0, 0);
    a11 = __builtin_amdgcn_mfma_f32_16x16x32_bf16(ah1, bh1, a11, 0, 0, 0);
    a00 = __builtin_amdgcn_mfma_f32_16x16x32_bf16(ah0, bl0, a00, 0, 0, 0);
    a01 = __builtin_amdgcn_mfma_f32_16x16x32_bf16(ah0, bl1, a01, 0, 0, 0);
    a10 = __builtin_amdgcn_mfma_f32_16x16x32_bf16(ah1, bl0, a10, 0, 0, 0);
    a11 = __builtin_amdgcn_mfma_f32_16x16x32_bf16(ah1, bl1, a11, 0, 0, 0);
    a00 = __builtin_amdgcn_mfma_f32_16x16x32_bf16(al0, bh0, a00, 0, 0, 0);
    a01 = __builtin_amdgcn_mfma_f32_16x16x32_bf16(al0, bh1, a01, 0, 0, 0);
    a10 = __builtin_amdgcn_mfma_f32_16x16x32_bf16(al1, bh0, a10, 0, 0, 0);
    a11 = __builtin_amdgcn_mfma_f32_16x16x32_bf16(al1, bh1, a11, 0, 0, 0);
  }
  float* pp = part + (size_t)(ks*NCAM + n)*FCc*PIX;
  int ocb = oc0 + ocr + ((lane >> 4) << 2);
  int pxb = px0 + pxr + (lane & 15);
  #pragma unroll
  for (int i = 0; i < 4; ++i) {
    pp[(size_t)(ocb + i)*PIX + pxb]           = a00[i];
    pp[(size_t)(ocb + i)*PIX + pxb + 16]      = a01[i];
    pp[(size_t)(ocb + 16 + i)*PIX + pxb]      = a10[i];
    pp[(size_t)(ocb + 16 + i)*PIX + pxb + 16] = a11[i];
  }
}

// bf16x3 MFMA GEMM for conv3 (1x1, K=128, bias fused, direct X3 write).
__global__ __launch_bounds__(256) void k_gemm_mfma3(
    const float* __restrict__ in, const float* ws,
    const float* __restrict__ bias, float* __restrict__ outbuf)
{
  __shared__ int alds[2][64*LROW];
  __shared__ int blds[2][64*LROW];
  int tid = threadIdx.x;
  int px0 = blockIdx.x * 64;
  int oc0 = blockIdx.y * 64;
  int n = blockIdx.z;
  const unsigned short* whi = (const unsigned short*)(ws + OFF_WT3);
  const unsigned short* wlo = whi + 24576;
  const float* inn = in + (size_t)n*FCc*PIX;
  int wv = tid >> 6, lane = tid & 63;
  int a_oc = tid >> 2, a_kq = tid & 3;
  int b_px = tid & 63, b_kq = tid >> 6;
  int p = px0 + b_px;

  i32x4 pa_h, pa_l; float bvv[8];
  auto issueA = [&](int s) {
    size_t gi = (size_t)(oc0 + a_oc)*128 + (s*32 + a_kq*8);
    pa_h = *(const i32x4*)(whi + gi);
    pa_l = *(const i32x4*)(wlo + gi);
  };
  auto issueB = [&](int s) {
    #pragma unroll
    for (int j = 0; j < 8; ++j) {
      int ic = s*32 + b_kq*8 + j;
      bvv[j] = inn[(size_t)ic*PIX + p];
    }
  };

  f32x4 a00 = {0.f,0.f,0.f,0.f}, a01 = a00, a10 = a00, a11 = a00;
  int ocr = (wv >> 1) * 32, pxr = (wv & 1) * 32;
  int dq = (lane >> 4) * 4;
  int rA0 = (ocr + (lane & 15)) * LROW + dq;
  int rA1 = rA0 + 16*LROW;
  int rB0 = (pxr + (lane & 15)) * LROW + dq;
  int rB1 = rB0 + 16*LROW;
  int aw = a_oc*LROW + a_kq*4;
  int bw = b_px*LROW + b_kq*4;

  issueA(0); issueB(0);
  for (int s = 0; s < 4; ++s) {
    __syncthreads();
    *(i32x4*)&alds[0][aw] = pa_h;
    *(i32x4*)&alds[1][aw] = pa_l;
    {
      i32x4 vh, vl;
      int th[8], tl[8];
      #pragma unroll
      for (int j = 0; j < 8; ++j) {
        unsigned short h = f2bf(bvv[j]);
        th[j] = h; tl[j] = f2bf(bvv[j] - bf2f(h));
      }
      vh.x = th[0]|(th[1]<<16); vh.y = th[2]|(th[3]<<16);
      vh.z = th[4]|(th[5]<<16); vh.w = th[6]|(th[7]<<16);
      vl.x = tl[0]|(tl[1]<<16); vl.y = tl[2]|(tl[3]<<16);
      vl.z = tl[4]|(tl[5]<<16); vl.w = tl[6]|(tl[7]<<16);
      *(i32x4*)&blds[0][bw] = vh;
      *(i32x4*)&blds[1][bw] = vl;
    }
    __syncthreads();
    if (s < 3) { issueA(s+1); issueB(s+1); }
    bf16x8 ah0 = *(bf16x8*)&alds[0][rA0], ah1 = *(bf16x8*)&alds[0][rA1];
    bf16x8 al0 = *(bf16x8*)&alds[1][rA0], al1 = *(bf16x8*)&alds[1][rA1];
    bf16x8 bh0 = *(bf16x8*)&blds[0][rB0], bh1 = *(bf16x8*)&blds[0][rB1];
    bf16x8 bl0 = *(bf16x8*)&blds[1][rB0], bl1 = *(bf16x8*)&blds[1][rB1];
    a00 = __builtin_amdgcn_mfma_f32_16x16x32_bf16(ah0, bh0, a00, 0, 0, 0);
    a01 = __builtin_amdgcn_mfma_f32_16x16x32_bf16(ah0, bh1, a01, 0, 0, 0);
    a10 = __builtin_amdgcn_mfma_f32_16x16x32_bf16(ah1, bh0, a10, 0, 0, 0);
    a11 = __builtin_amdgcn_mfma_f32_16x16x32_bf16(ah1, bh1, a11, 0, 0, 0);
    a00 = __builtin_amdgcn_mfma_f32_16x16x32_bf16(ah0, bl0, a00, 0, 0, 0);
    a01 = __builtin_amdgcn_mfma_f32_16x16x32_bf16(ah0, bl1, a01, 0, 0, 0);
    a10 = __builtin_amdgcn_mfma_f32_16x16x32_bf16(ah1, bl0, a10, 0, 0, 0);
    a11 = __builtin_amdgcn_mfma_f32_16x16x32_bf16(ah1, bl1, a11, 0, 0, 0);
    a00 = __builtin_amdgcn_mfma_f32_16x16x32_bf16(al0, bh0, a00, 0, 0, 0);
    a01 = __builtin_amdgcn_mfma_f32_16x16x32_bf16(al0, bh1, a01, 0, 0, 0);
    a10 = __builtin_amdgcn_mfma_f32_16x16x32_bf16(al1, bh0, a10, 0, 0, 0);
    a11 = __builtin_amdgcn_mfma_f32_16x16x32_bf16(al1, bh1, a11, 0, 0, 0);
  }
  int ocb = oc0 + ocr + ((lane >> 4) << 2);
  int pxb = px0 + pxr + (lane & 15);
  #pragma unroll
  for (int i = 0; i < 4; ++i) {
    int o0 = ocb + i, o1 = ocb + 16 + i;
    if (o0 < C3) {
      float b = bias[o0];
      outbuf[(size_t)(n*C3 + o0)*PIX + pxb]      = a00[i] + b;
      outbuf[(size_t)(n*C3 + o0)*PIX + pxb + 16] = a01[i] + b;
    }
    if (o1 < C3) {
      float b = bias[o1];
      outbuf[(size_t)(n*C3 + o1)*PIX + pxb]      = a10[i] + b;
      outbuf[(size_t)(n*C3 + o1)*PIX + pxb + 16] = a11[i] + b;
    }
  }
}

__global__ void k_epi_bn(const float* __restrict__ part, const float* __restrict__ cb,
                         const float* __restrict__ g, const float* __restrict__ be,
                         const float* __restrict__ mn, const float* __restrict__ vr,
                         float* __restrict__ out, int KSPLIT)
{
  int idx = blockIdx.x*256 + threadIdx.x;
  if (idx >= NCAM*FCc*176) return;
  int px4 = idx % 176;
  int t = idx / 176;
  int oc = t % FCc;
  int n = t / FCc;
  float4 s = {0.f,0.f,0.f,0.f};
  for (int ks = 0; ks < KSPLIT; ++ks) {
    const float4* p = (const float4*)(part + (size_t)((ks*NCAM+n)*FCc + oc)*PIX);
    float4 v = p[px4];
    s.x += v.x; s.y += v.y; s.z += v.z; s.w += v.w;
  }
  float inv = g[oc] * rsqrtf(vr[oc] + 1e-3f);
  float sh = (cb[oc] - mn[oc]) * inv + be[oc];
  float4 o;
  o.x = fmaxf(s.x*inv + sh, 0.f);
  o.y = fmaxf(s.y*inv + sh, 0.f);
  o.z = fmaxf(s.z*inv + sh, 0.f);
  o.w = fmaxf(s.w*inv + sh, 0.f);
  ((float4*)(out + (size_t)(n*FCc + oc)*PIX))[px4] = o;
}

// Coalesced moments (R21): block = 64 hw x 4 waves (lane = hw).
__global__ __launch_bounds__(256) void k_moments(float* __restrict__ ws) {
  __shared__ float r0[4][64], r1[4][64], r2[4][64];
  __shared__ float tile[64][65];
  int tid = threadIdx.x;
  int w = tid >> 6, l = tid & 63;
  int n = blockIdx.x / 11, hw0 = (blockIdx.x % 11) * 64;
  int hw = hw0 + l;
  const float* x3 = ws + OFF_X3 + (size_t)n*C3*PIX;
  const float2* geo = (const float2*)(ws + OFF_GEO);
  float le[12], gxr[12], gyr[12];
  float pm = -1e30f;
  #pragma unroll
  for (int j = 0; j < 12; ++j) {
    le[j] = x3[(size_t)(w*12 + j)*PIX + hw];
    pm = fmaxf(pm, le[j]);
  }
  r0[w][l] = pm;
  __syncthreads();
  float mx = fmaxf(fmaxf(r0[0][l], r0[1][l]), fmaxf(r0[2][l], r0[3][l]));
  __syncthreads();
  float s_p = 0.f, sx_p = 0.f, sy_p = 0.f;
  #pragma unroll
  for (int j = 0; j < 12; ++j) {
    float e = expf(le[j] - mx);
    le[j] = e;
    float2 g2 = geo[(size_t)(n*DB + w*12 + j)*PIX + hw];
    gxr[j] = g2.x; gyr[j] = g2.y;
    s_p += e; sx_p += e*g2.x; sy_p += e*g2.y;
  }
  r0[w][l] = s_p; r1[w][l] = sx_p; r2[w][l] = sy_p;
  __syncthreads();
  float s  = r0[0][l] + r0[1][l] + r0[2][l] + r0[3][l];
  float sx = (r1[0][l] + r1[1][l] + r1[2][l] + r1[3][l]) / s;
  float sy = (r2[0][l] + r2[1][l] + r2[2][l] + r2[3][l]) / s;
  __syncthreads();
  float cxx = 0.f, cxy = 0.f, cyy = 0.f;
  #pragma unroll
  for (int j = 0; j < 12; ++j) {
    float dx = gxr[j] - sx, dy = gyr[j] - sy;
    cxx += le[j]*dx*dx; cxy += le[j]*dx*dy; cyy += le[j]*dy*dy;
  }
  r0[w][l] = cxx; r1[w][l] = cxy; r2[w][l] = cyy;
  __syncthreads();
  if (w == 0) {
    float c00 = (r0[0][l] + r0[1][l] + r0[2][l] + r0[3][l]) / s;
    float c01 = (r1[0][l] + r1[1][l] + r1[2][l] + r1[3][l]) / s;
    float c11 = (r2[0][l] + r2[1][l] + r2[2][l] + r2[3][l]) / s;
    float opl = x3[(size_t)DB*PIX + hw];
    float opac = 1.f / (1.f + expf(-opl));
    float a = c11*(1.f/9.f) + 0.3f;
    float b = c01*(1.f/9.f);
    float c = c00*(1.f/9.f) + 0.3f;
    float py = 50.f - sy;
    float px = 50.f - sx;
    float det = a*c - b*b;
    float op = (opac > 0.05f) ? opac : 0.f;
    float invd = 1.f;
    if (det > 0.f) invd = 1.f/det; else op = 0.f;
    float lop = (op > 0.f) ? logf(op) : -1e30f;
    int wid = n*PIX + hw;
    ((float4*)(ws + OFF_PRM))[wid]  = make_float4(py, px, -0.5f*c*invd, -0.5f*a*invd);
    ((float2*)(ws + OFF_PRM2))[wid] = make_float2(b*invd, lop);
  }
  float* ft = ws + OFF_FEATT;
  for (int half = 0; half < 2; ++half) {
    __syncthreads();
    int ch0 = half*64;
    #pragma unroll
    for (int r = 0; r < 16; ++r) {
      int ch = w*16 + r;
      tile[ch][l] = x3[(size_t)(DB + 1 + ch0 + ch)*PIX + hw];
    }
    __syncthreads();
    #pragma unroll
    for (int k = 0; k < 16; ++k) {
      int h = w + 4*k;
      ft[(size_t)(n*PIX + hw0 + h)*128 + ch0 + l] = tile[l][h];
    }
  }
}

template<int CTRL, int RMASK>
__device__ __forceinline__ float dpp_mul(float v) {
  int t = __builtin_amdgcn_update_dpp(0x3f800000, __float_as_int(v), CTRL, RMASK, 0xF, false);
  return v * __int_as_float(t);
}

// Split-K raster, NSPLIT=6 (11 groups/split, 16.9KB LDS): halved block
// duration -> finer tail granularity. Inner loop identical to R20/R21.
__global__ __launch_bounds__(512) void k_raster(const float* __restrict__ ws,
                                                float* __restrict__ wsout) {
  __shared__ float4 s4[SG];
  __shared__ float2 s2[SG];
  int lane = threadIdx.x & 63, wv = threadIdx.x >> 6;
  int split = blockIdx.x / 1250;
  int pxb   = blockIdx.x % 1250;
  int pix = pxb * 8 + wv;
  float yi = (float)(pix / 100), xi = (float)(pix % 100);
  int gbase = split * SG;
  const float4* prm4 = (const float4*)(ws + OFF_PRM) + gbase;
  const float2* prm2 = (const float2*)(ws + OFF_PRM2) + gbase;
  const float2* ft = (const float2*)(ws + OFF_FEATT);
  for (int i = threadIdx.x; i < SG; i += 512) {
    s4[i] = prm4[i];
    s2[i] = prm2[i];
  }
  __syncthreads();
  float T = 1.f, ax = 0.f, ay = 0.f;
  for (int gl = 0; gl < SG; gl += 64) {
    float4 c4 = s4[gl + lane];
    float2 c2 = s2[gl + lane];
    float dyv = c4.x - yi, dxv = c4.y - xi;
    float pw = c4.z*dyv*dyv + c4.w*dxv*dxv + c2.x*dyv*dxv;
    float t  = pw + c2.y;                       // pw + log(op)
    bool hit = (t >= TH_LOG);
    unsigned long long m0 = __ballot(hit);
    if (m0) {
      float alpha = __expf(fminf(t, c2.y));     // op*exp(min(pw,0))
      alpha = fminf(alpha, 0.99f);
      alpha = hit ? alpha : 0.f;
      float P = 1.f - alpha;
      P = dpp_mul<0x111, 0xF>(P);
      P = dpp_mul<0x112, 0xF>(P);
      P = dpp_mul<0x114, 0xF>(P);
      P = dpp_mul<0x118, 0xF>(P);
      P = dpp_mul<0x142, 0xA>(P);
      P = dpp_mul<0x143, 0xC>(P);
      float E = __int_as_float(__builtin_amdgcn_update_dpp(
                  0x3f800000, __float_as_int(P), 0x138, 0xF, 0xF, false));
      float w = alpha * T * E;
      T *= __int_as_float(__builtin_amdgcn_readlane(__float_as_int(P), 63));
      unsigned long long mask = __ballot(w > 1e-9f);
      int g0 = gbase + gl;
      while (mask) {
        int jj[8];
        #pragma unroll
        for (int b = 0; b < 8; ++b) {
          if (mask) { jj[b] = __builtin_ctzll(mask); mask &= mask - 1ull; }
          else jj[b] = -1;
        }
        float2 fb[8]; float wb[8];
        #pragma unroll
        for (int b = 0; b < 8; ++b) {
          int j = (jj[b] >= 0) ? jj[b] : jj[0];
          fb[b] = ft[(size_t)(g0 + j)*64 + lane];
          wb[b] = (jj[b] >= 0)
            ? __int_as_float(__builtin_amdgcn_readlane(__float_as_int(w), jj[b]))
            : 0.f;
        }
        #pragma unroll
        for (int b = 0; b < 8; ++b) { ax += wb[b]*fb[b].x; ay += wb[b]*fb[b].y; }
      }
      if (T < 1e-7f) break;                     // local exit (error < 1e-7)
    }
  }
  unsigned* sfu = (unsigned*)(wsout + OFF_SF);
  sfu[((size_t)split*BEVN + pix)*64 + lane] =
      (unsigned)f2bf(ax) | ((unsigned)f2bf(ay) << 16);
  if (lane == 0) (wsout + OFF_SP)[split*BEVN + pix] = T;
}

// ordered combine over 6 splits: F = sum_s (prod_{t<s} T_t) * F_s
__global__ __launch_bounds__(512) void k_combine(const float* __restrict__ ws,
                                                 float* __restrict__ out) {
  int lane = threadIdx.x & 63, wv = threadIdx.x >> 6;
  int pix = blockIdx.x * 8 + wv;
  const float* sp = ws + OFF_SP;
  const unsigned* sfu = (const unsigned*)(ws + OFF_SF);
  float T = 1.f, ox = 0.f, oy = 0.f;
  #pragma unroll
  for (int s = 0; s < NSPLIT; ++s) {
    unsigned u = sfu[((size_t)s*BEVN + pix)*64 + lane];
    ox += T * bf2f((unsigned short)(u & 0xffff));
    oy += T * bf2f((unsigned short)(u >> 16));
    T *= sp[s*BEVN + pix];
  }
  out[(size_t)(2*lane)*BEVN + pix]   = ox;
  out[(size_t)(2*lane+1)*BEVN + pix] = oy;
}

extern "C" void kernel_launch(void* const* d_in, const int* in_sizes, int n_in,
                              void* d_out, int out_size, void* d_ws, size_t ws_size,
                              hipStream_t stream) {
  const float* rot        = (const float*)d_in[0];
  const float* trans      = (const float*)d_in[1];
  const float* intr       = (const float*)d_in[2];
  const float* post_rot   = (const float*)d_in[3];
  const float* post_trans = (const float*)d_in[4];
  const float* img        = (const float*)d_in[5];
  const float* w1  = (const float*)d_in[6];
  const float* b1  = (const float*)d_in[7];
  const float* g1  = (const float*)d_in[8];
  const float* be1 = (const float*)d_in[9];
  const float* m1  = (const float*)d_in[10];
  const float* v1  = (const float*)d_in[11];
  const float* w2  = (const float*)d_in[12];
  const float* b2  = (const float*)d_in[13];
  const float* g2  = (const float*)d_in[14];
  const float* be2 = (const float*)d_in[15];
  const float* m2  = (const float*)d_in[16];
  const float* v2  = (const float*)d_in[17];
  const float* w3  = (const float*)d_in[18];
  const float* b3  = (const float*)d_in[19];
  float* ws  = (float*)d_ws;
  float* out = (float*)d_out;

  k_prep<<<1368, 256, 0, stream>>>(rot, intr, post_rot, trans, post_trans,
                                   w1, w2, w3, ws);

  // conv1: bf16x3 MFMA, K=1152, KSPLIT=4
  k_gemm_mfma<<<dim3(11,2,24), 256, 0, stream>>>(img, ws, ws+OFF_PART, OFF_WT1);
  k_epi_bn<<<528, 256, 0, stream>>>(ws+OFF_PART, b1, g1, be1, m1, v1, ws+OFF_X1, 4);
  // conv2
  k_gemm_mfma<<<dim3(11,2,24), 256, 0, stream>>>(ws+OFF_X1, ws, ws+OFF_PART, OFF_WT2);
  k_epi_bn<<<528, 256, 0, stream>>>(ws+OFF_PART, b2, g2, be2, m2, v2, ws+OFF_X2, 4);
  // conv3: 1x1, K=128, bf16x3 MFMA, bias fused, direct X3 write
  k_gemm_mfma3<<<dim3(11,3,6), 256, 0, stream>>>(ws+OFF_X2, ws, b3, ws+OFF_X3);

  k_moments<<<66, 256, 0, stream>>>(ws);
  k_raster<<<7500, 512, 0, stream>>>(ws, ws);
  k_combine<<<1250, 512, 0, stream>>>(ws, out);
}

// Round 23
// 112.505 us; speedup vs baseline: 1.2641x; 1.0361x over previous
//
#include <hip/hip_runtime.h>
#include <math.h>

#define NCAM 6
#define FHh 16
#define FWw 44
#define PIX 704            // FHh*FWw
#define FCc 128
#define DB 48
#define C3 177             // DB + 1 + 128
#define KCONV 1152         // FCc*9
#define NG 4224            // NCAM*PIX
#define BEVN 10000
#define NSPLIT 6
#define SG 704             // gaussians per split (11 groups of 64)
#define TH_LOG (-5.5412635f)   // -ln(255): alpha>=1/255  <=>  pw+lop >= TH_LOG

// ---- ws layout (float offsets) ----
#define OFF_WT1    0                           // bf16 hi/lo ushorts (147456 floats)
#define OFF_WT2    147456
#define OFF_WT3    294912                      // bf16 hi/lo [192][128] (24576 floats)
#define OFF_GEO    319488                      // [6*48*704][2]
#define OFF_X1     724992                      // [6][128][704] packed uint hi|lo
#define OFF_X2     1265664                     // imgbf during conv1, then X2 packed
#define OFF_X3     1806336                     // [6][177][704] f32
#define OFF_PART   2553984                     // [4][6][128][704] conv partials
#define OFF_PRM    4716672                     // float4 [NG]: py,px,qc,qa
#define OFF_PRM2   4733568                     // float2 [NG]: qb,lop
#define OFF_FEATT  4742016                     // [NG][128] f32
#define OFF_SF     0                           // [NSPLIT][BEVN][64] uints (packed bf16 partials)
#define OFF_SP     3840000                     // [NSPLIT][BEVN] local transmittance
// end = 5,282,688 floats = 21.1 MiB

typedef __attribute__((ext_vector_type(8))) short bf16x8;
typedef __attribute__((ext_vector_type(4))) float f32x4;
typedef __attribute__((ext_vector_type(4))) int i32x4;

__device__ __forceinline__ unsigned short f2bf(float x) {
  unsigned u = __float_as_uint(x);
  return (unsigned short)((u + 0x7FFF + ((u >> 16) & 1)) >> 16);
}
__device__ __forceinline__ float bf2f(unsigned short h) {
  return __uint_as_float(((unsigned)h) << 16);
}
__device__ __forceinline__ unsigned packsplit(float x) {   // hi | lo<<16
  unsigned short h = f2bf(x);
  unsigned short l = f2bf(x - bf2f(h));
  return (unsigned)h | ((unsigned)l << 16);
}

__device__ __forceinline__ void inv3(const float* A, float* I) {
  float a=A[0],b=A[1],c=A[2],d=A[3],e=A[4],f=A[5],g=A[6],h=A[7],i=A[8];
  float c0 = e*i - f*h, c1 = f*g - d*i, c2 = d*h - e*g;
  float det = a*c0 + b*c1 + c*c2;
  float id = 1.f/det;
  I[0]=c0*id; I[1]=(c*h-b*i)*id; I[2]=(b*f-c*e)*id;
  I[3]=c1*id; I[4]=(a*i-c*g)*id; I[5]=(c*d-a*f)*id;
  I[6]=c2*id; I[7]=(b*g-a*h)*id; I[8]=(a*e-b*d)*id;
}

// fused: [0,792) geometry; [792,1368) weights; [1368,3480) img -> packed bf16
__global__ void k_prep(const float* __restrict__ rot, const float* __restrict__ intr,
                       const float* __restrict__ post_rot,
                       const float* __restrict__ trans, const float* __restrict__ post_trans,
                       const float* __restrict__ w1, const float* __restrict__ w2,
                       const float* __restrict__ w3, const float* __restrict__ img,
                       float* __restrict__ ws) {
  if (blockIdx.x < 792) {
    __shared__ float sm[NCAM][24];
    if (threadIdx.x < NCAM) {
      int n = threadIdx.x;
      float ip[9], ii[9];
      inv3(post_rot + n*9, ip);
      inv3(intr + n*9, ii);
      const float* R = rot + n*9;
      for (int j = 0; j < 9; ++j) sm[n][j] = ip[j];
      for (int r = 0; r < 3; ++r)
        for (int c = 0; c < 3; ++c) {
          float s = 0.f;
          for (int k = 0; k < 3; ++k) s += R[r*3+k]*ii[k*3+c];
          sm[n][9 + r*3 + c] = s;
        }
    }
    __syncthreads();
    int idx = blockIdx.x*256 + threadIdx.x;
    if (idx >= NCAM*DB*PIX) return;
    int n = idx / (DB*PIX);
    int rem = idx % (DB*PIX);
    int d = rem / PIX;
    int hw = rem % PIX;
    int h = hw / FWw, w = hw % FWw;
    float fx = w * (351.0f/43.0f);
    float fy = h * (127.0f/15.0f);
    float fz = 1.0f + (float)d;
    const float* pt = post_trans + n*3;
    float v0 = fx - pt[0], v1 = fy - pt[1], v2 = fz - pt[2];
    const float* m = sm[n];
    float x = m[0]*v0 + m[1]*v1 + m[2]*v2;
    float y = m[3]*v0 + m[4]*v1 + m[5]*v2;
    float z = m[6]*v0 + m[7]*v1 + m[8]*v2;
    float q0 = x*z, q1 = y*z, q2 = z;
    const float* c = m + 9;
    const float* t = trans + n*3;
    float gx = c[0]*q0 + c[1]*q1 + c[2]*q2 + t[0];
    float gy = c[3]*q0 + c[4]*q1 + c[5]*q2 + t[1];
    ((float2*)(ws + OFF_GEO))[idx] = make_float2(gx, gy);
  } else if (blockIdx.x < 1368) {
    int e = (blockIdx.x - 792)*256 + threadIdx.x;
    if (e < 147456) {
      float v1 = w1[e], v2 = w2[e];
      unsigned short h1 = f2bf(v1), h2 = f2bf(v2);
      unsigned short l1 = f2bf(v1 - bf2f(h1)), l2 = f2bf(v2 - bf2f(h2));
      unsigned short* wt1 = (unsigned short*)(ws + OFF_WT1);
      unsigned short* wt2 = (unsigned short*)(ws + OFF_WT2);
      wt1[e] = h1; wt1[147456 + e] = l1;
      wt2[e] = h2; wt2[147456 + e] = l2;
    }
    if (e < 192*128) {                   // conv3: [oc<192][k<128], zero-pad oc>=177
      int oc = e >> 7, k = e & 127;
      float v = (oc < C3) ? w3[oc*FCc + k] : 0.f;
      unsigned short h = f2bf(v);
      unsigned short* wt3 = (unsigned short*)(ws + OFF_WT3);
      wt3[e] = h; wt3[24576 + e] = f2bf(v - bf2f(h));
    }
  } else {
    int e = (blockIdx.x - 1368)*256 + threadIdx.x;
    if (e < NCAM*FCc*PIX)
      ((unsigned*)(ws + OFF_X2))[e] = packsplit(img[e]);   // imgbf in X2 slot
  }
}

#define LROW 20   // dwords per LDS row: 32 bf16 = 16 dw + 4 pad

// bf16x3 MFMA im2col GEMM, 3x3 convs. Block 256 thr = 4 waves, 64oc x 64px,
// Kchunk 288 (9 steps of K=32). Input is PACKED bf16 (hi|lo<<16): staging is
// 1 uint load + 2 bit-ops per element instead of f2bf arithmetic.
__global__ __launch_bounds__(256) void k_gemm_mfma(
    const unsigned* __restrict__ in, const float* ws, float* __restrict__ part, int woff)
{
  __shared__ int alds[2][64*LROW];
  __shared__ int blds[2][64*LROW];
  int tid = threadIdx.x;
  int px0 = blockIdx.x * 64;
  int oc0 = blockIdx.y * 64;
  int z = blockIdx.z; int n = z >> 2, ks = z & 3;
  const unsigned short* whi = (const unsigned short*)(ws + woff);
  const unsigned short* wlo = whi + 147456;
  const unsigned* inn = in + (size_t)n*FCc*PIX;
  int wv = tid >> 6, lane = tid & 63;
  int a_oc = tid >> 2, a_kq = tid & 3;
  int b_px = tid & 63, b_kq = tid >> 6;
  int p = px0 + b_px; int b_y = p / FWw, b_x = p - b_y*FWw;
  int k00 = ks * 288;

  i32x4 pa_h, pa_l; unsigned bu[8];
  auto issueA = [&](int s) {
    size_t gi = (size_t)(oc0 + a_oc)*KCONV + (k00 + s*32 + a_kq*8);
    pa_h = *(const i32x4*)(whi + gi);
    pa_l = *(const i32x4*)(wlo + gi);
  };
  auto issueB = [&](int s) {
    #pragma unroll
    for (int j = 0; j < 8; ++j) {
      int k = k00 + s*32 + b_kq*8 + j;
      int ic = k / 9, tap = k - ic*9;
      int ky = tap / 3, kx = tap - ky*3;
      int yy = b_y + ky - 1, xx = b_x + kx - 1;
      unsigned v = 0u;
      if ((unsigned)yy < FHh && (unsigned)xx < FWw) v = inn[(size_t)ic*PIX + yy*FWw + xx];
      bu[j] = v;
    }
  };

  f32x4 a00 = {0.f,0.f,0.f,0.f}, a01 = a00, a10 = a00, a11 = a00;
  int ocr = (wv >> 1) * 32, pxr = (wv & 1) * 32;
  int dq = (lane >> 4) * 4;
  int rA0 = (ocr + (lane & 15)) * LROW + dq;
  int rA1 = rA0 + 16*LROW;
  int rB0 = (pxr + (lane & 15)) * LROW + dq;
  int rB1 = rB0 + 16*LROW;
  int aw = a_oc*LROW + a_kq*4;
  int bw = b_px*LROW + b_kq*4;

  issueA(0); issueB(0);
  for (int s = 0; s < 9; ++s) {
    __syncthreads();
    *(i32x4*)&alds[0][aw] = pa_h;
    *(i32x4*)&alds[1][aw] = pa_l;
    {
      i32x4 vh, vl;
      int th[8], tl[8];
      #pragma unroll
      for (int j = 0; j < 8; ++j) { th[j] = bu[j] & 0xffff; tl[j] = bu[j] >> 16; }
      vh.x = th[0]|(th[1]<<16); vh.y = th[2]|(th[3]<<16);
      vh.z = th[4]|(th[5]<<16); vh.w = th[6]|(th[7]<<16);
      vl.x = tl[0]|(tl[1]<<16); vl.y = tl[2]|(tl[3]<<16);
      vl.z = tl[4]|(tl[5]<<16); vl.w = tl[6]|(tl[7]<<16);
      *(i32x4*)&blds[0][bw] = vh;
      *(i32x4*)&blds[1][bw] = vl;
    }
    __syncthreads();
    if (s < 8) { issueA(s+1); issueB(s+1); }
    bf16x8 ah0 = *(bf16x8*)&alds[0][rA0], ah1 = *(bf16x8*)&alds[0][rA1];
    bf16x8 al0 = *(bf16x8*)&alds[1][rA0], al1 = *(bf16x8*)&alds[1][rA1];
    bf16x8 bh0 = *(bf16x8*)&blds[0][rB0], bh1 = *(bf16x8*)&blds[0][rB1];
    bf16x8 bl0 = *(bf16x8*)&blds[1][rB0], bl1 = *(bf16x8*)&blds[1][rB1];
    a00 = __builtin_amdgcn_mfma_f32_16x16x32_bf16(ah0, bh0, a00, 0, 0, 0);
    a01 = __builtin_amdgcn_mfma_f32_16x16x32_bf16(ah0, bh1, a01, 0, 0, 0);
    a10 = __builtin_amdgcn_mfma_f32_16x16x32_bf16(ah1, bh0, a10, 0, 0, 0);
    a11 = __builtin_amdgcn_mfma_f32_16x16x32_bf16(ah1, bh1, a11, 0, 0, 0);
    a00 = __builtin_amdgcn_mfma_f32_16x16x32_bf16(ah0, bl0, a00, 0, 0, 0);
    a01 = __builtin_amdgcn_mfma_f32_16x16x32_bf16(ah0, bl1, a01, 0, 0, 0);
    a10 = __builtin_amdgcn_mfma_f32_16x16x32_bf16(ah1, bl0, a10, 0, 0, 0);
    a11 = __builtin_amdgcn_mfma_f32_16x16x32_bf16(ah1, bl1, a11, 0, 0, 0);
    a00 = __builtin_amdgcn_mfma_f32_16x16x32_bf16(al0, bh0, a00, 0, 0, 0);
    a01 = __builtin_amdgcn_mfma_f32_16x16x32_bf16(al0, bh1, a01, 0, 0, 0);
    a10 = __builtin_amdgcn_mfma_f32_16x16x32_bf16(al1, bh0, a10, 0, 0, 0);
    a11 = __builtin_amdgcn_mfma_f32_16x16x32_bf16(al1, bh1, a11, 0, 0, 0);
  }
  float* pp = part + (size_t)(ks*NCAM + n)*FCc*PIX;
  int ocb = oc0 + ocr + ((lane >> 4) << 2);
  int pxb = px0 + pxr + (lane & 15);
  #pragma unroll
  for (int i = 0; i < 4; ++i) {
    pp[(size_t)(ocb + i)*PIX + pxb]           = a00[i];
    pp[(size_t)(ocb + i)*PIX + pxb + 16]      = a01[i];
    pp[(size_t)(ocb + 16 + i)*PIX + pxb]      = a10[i];
    pp[(size_t)(ocb + 16 + i)*PIX + pxb + 16] = a11[i];
  }
}

// bf16x3 MFMA GEMM for conv3 (1x1, K=128, bias fused, direct X3 f32 write).
// Input X2 is packed bf16.
__global__ __launch_bounds__(256) void k_gemm_mfma3(
    const unsigned* __restrict__ in, const float* ws,
    const float* __restrict__ bias, float* __restrict__ outbuf)
{
  __shared__ int alds[2][64*LROW];
  __shared__ int blds[2][64*LROW];
  int tid = threadIdx.x;
  int px0 = blockIdx.x * 64;
  int oc0 = blockIdx.y * 64;
  int n = blockIdx.z;
  const unsigned short* whi = (const unsigned short*)(ws + OFF_WT3);
  const unsigned short* wlo = whi + 24576;
  const unsigned* inn = in + (size_t)n*FCc*PIX;
  int wv = tid >> 6, lane = tid & 63;
  int a_oc = tid >> 2, a_kq = tid & 3;
  int b_px = tid & 63, b_kq = tid >> 6;
  int p = px0 + b_px;

  i32x4 pa_h, pa_l; unsigned bu[8];
  auto issueA = [&](int s) {
    size_t gi = (size_t)(oc0 + a_oc)*128 + (s*32 + a_kq*8);
    pa_h = *(const i32x4*)(whi + gi);
    pa_l = *(const i32x4*)(wlo + gi);
  };
  auto issueB = [&](int s) {
    #pragma unroll
    for (int j = 0; j < 8; ++j) {
      int ic = s*32 + b_kq*8 + j;
      bu[j] = inn[(size_t)ic*PIX + p];
    }
  };

  f32x4 a00 = {0.f,0.f,0.f,0.f}, a01 = a00, a10 = a00, a11 = a00;
  int ocr = (wv >> 1) * 32, pxr = (wv & 1) * 32;
  int dq = (lane >> 4) * 4;
  int rA0 = (ocr + (lane & 15)) * LROW + dq;
  int rA1 = rA0 + 16*LROW;
  int rB0 = (pxr + (lane & 15)) * LROW + dq;
  int rB1 = rB0 + 16*LROW;
  int aw = a_oc*LROW + a_kq*4;
  int bw = b_px*LROW + b_kq*4;

  issueA(0); issueB(0);
  for (int s = 0; s < 4; ++s) {
    __syncthreads();
    *(i32x4*)&alds[0][aw] = pa_h;
    *(i32x4*)&alds[1][aw] = pa_l;
    {
      i32x4 vh, vl;
      int th[8], tl[8];
      #pragma unroll
      for (int j = 0; j < 8; ++j) { th[j] = bu[j] & 0xffff; tl[j] = bu[j] >> 16; }
      vh.x = th[0]|(th[1]<<16); vh.y = th[2]|(th[3]<<16);
      vh.z = th[4]|(th[5]<<16); vh.w = th[6]|(th[7]<<16);
      vl.x = tl[0]|(tl[1]<<16); vl.y = tl[2]|(tl[3]<<16);
      vl.z = tl[4]|(tl[5]<<16); vl.w = tl[6]|(tl[7]<<16);
      *(i32x4*)&blds[0][bw] = vh;
      *(i32x4*)&blds[1][bw] = vl;
    }
    __syncthreads();
    if (s < 3) { issueA(s+1); issueB(s+1); }
    bf16x8 ah0 = *(bf16x8*)&alds[0][rA0], ah1 = *(bf16x8*)&alds[0][rA1];
    bf16x8 al0 = *(bf16x8*)&alds[1][rA0], al1 = *(bf16x8*)&alds[1][rA1];
    bf16x8 bh0 = *(bf16x8*)&blds[0][rB0], bh1 = *(bf16x8*)&blds[0][rB1];
    bf16x8 bl0 = *(bf16x8*)&blds[1][rB0], bl1 = *(bf16x8*)&blds[1][rB1];
    a00 = __builtin_amdgcn_mfma_f32_16x16x32_bf16(ah0, bh0, a00, 0, 0, 0);
    a01 = __builtin_amdgcn_mfma_f32_16x16x32_bf16(ah0, bh1, a01, 0, 0, 0);
    a10 = __builtin_amdgcn_mfma_f32_16x16x32_bf16(ah1, bh0, a10, 0, 0, 0);
    a11 = __builtin_amdgcn_mfma_f32_16x16x32_bf16(ah1, bh1, a11, 0, 0, 0);
    a00 = __builtin_amdgcn_mfma_f32_16x16x32_bf16(ah0, bl0, a00, 0, 0, 0);
    a01 = __builtin_amdgcn_mfma_f32_16x16x32_bf16(ah0, bl1, a01, 0, 0, 0);
    a10 = __builtin_amdgcn_mfma_f32_16x16x32_bf16(ah1, bl0, a10, 0, 0, 0);
    a11 = __builtin_amdgcn_mfma_f32_16x16x32_bf16(ah1, bl1, a11, 0, 0, 0);
    a00 = __builtin_amdgcn_mfma_f32_16x16x32_bf16(al0, bh0, a00, 0, 0, 0);
    a01 = __builtin_amdgcn_mfma_f32_16x16x32_bf16(al0, bh1, a01, 0, 0, 0);
    a10 = __builtin_amdgcn_mfma_f32_16x16x32_bf16(al1, bh0, a10, 0, 0, 0);
    a11 = __builtin_amdgcn_mfma_f32_16x16x32_bf16(al1, bh1, a11, 0, 0, 0);
  }
  int ocb = oc0 + ocr + ((lane >> 4) << 2);
  int pxb = px0 + pxr + (lane & 15);
  #pragma unroll
  for (int i = 0; i < 4; ++i) {
    int o0 = ocb + i, o1 = ocb + 16 + i;
    if (o0 < C3) {
      float b = bias[o0];
      outbuf[(size_t)(n*C3 + o0)*PIX + pxb]      = a00[i] + b;
      outbuf[(size_t)(n*C3 + o0)*PIX + pxb + 16] = a01[i] + b;
    }
    if (o1 < C3) {
      float b = bias[o1];
      outbuf[(size_t)(n*C3 + o1)*PIX + pxb]      = a10[i] + b;
      outbuf[(size_t)(n*C3 + o1)*PIX + pxb + 16] = a11[i] + b;
    }
  }
}

// epilogue: KSPLIT reduce + BN + ReLU, output PACKED bf16 (hi|lo<<16)
__global__ void k_epi_bn(const float* __restrict__ part, const float* __restrict__ cb,
                         const float* __restrict__ g, const float* __restrict__ be,
                         const float* __restrict__ mn, const float* __restrict__ vr,
                         float* __restrict__ out, int KSPLIT)
{
  int idx = blockIdx.x*256 + threadIdx.x;
  if (idx >= NCAM*FCc*176) return;
  int px4 = idx % 176;
  int t = idx / 176;
  int oc = t % FCc;
  int n = t / FCc;
  float4 s = {0.f,0.f,0.f,0.f};
  for (int ks = 0; ks < KSPLIT; ++ks) {
    const float4* p = (const float4*)(part + (size_t)((ks*NCAM+n)*FCc + oc)*PIX);
    float4 v = p[px4];
    s.x += v.x; s.y += v.y; s.z += v.z; s.w += v.w;
  }
  float inv = g[oc] * rsqrtf(vr[oc] + 1e-3f);
  float sh = (cb[oc] - mn[oc]) * inv + be[oc];
  uint4 o;
  o.x = packsplit(fmaxf(s.x*inv + sh, 0.f));
  o.y = packsplit(fmaxf(s.y*inv + sh, 0.f));
  o.z = packsplit(fmaxf(s.z*inv + sh, 0.f));
  o.w = packsplit(fmaxf(s.w*inv + sh, 0.f));
  ((uint4*)((unsigned*)out + (size_t)(n*FCc + oc)*PIX))[px4] = o;
}

// Coalesced moments (R21): block = 64 hw x 4 waves (lane = hw).
__global__ __launch_bounds__(256) void k_moments(float* __restrict__ ws) {
  __shared__ float r0[4][64], r1[4][64], r2[4][64];
  __shared__ float tile[64][65];
  int tid = threadIdx.x;
  int w = tid >> 6, l = tid & 63;
  int n = blockIdx.x / 11, hw0 = (blockIdx.x % 11) * 64;
  int hw = hw0 + l;
  const float* x3 = ws + OFF_X3 + (size_t)n*C3*PIX;
  const float2* geo = (const float2*)(ws + OFF_GEO);
  float le[12], gxr[12], gyr[12];
  float pm = -1e30f;
  #pragma unroll
  for (int j = 0; j < 12; ++j) {
    le[j] = x3[(size_t)(w*12 + j)*PIX + hw];
    pm = fmaxf(pm, le[j]);
  }
  r0[w][l] = pm;
  __syncthreads();
  float mx = fmaxf(fmaxf(r0[0][l], r0[1][l]), fmaxf(r0[2][l], r0[3][l]));
  __syncthreads();
  float s_p = 0.f, sx_p = 0.f, sy_p = 0.f;
  #pragma unroll
  for (int j = 0; j < 12; ++j) {
    float e = expf(le[j] - mx);
    le[j] = e;
    float2 g2 = geo[(size_t)(n*DB + w*12 + j)*PIX + hw];
    gxr[j] = g2.x; gyr[j] = g2.y;
    s_p += e; sx_p += e*g2.x; sy_p += e*g2.y;
  }
  r0[w][l] = s_p; r1[w][l] = sx_p; r2[w][l] = sy_p;
  __syncthreads();
  float s  = r0[0][l] + r0[1][l] + r0[2][l] + r0[3][l];
  float sx = (r1[0][l] + r1[1][l] + r1[2][l] + r1[3][l]) / s;
  float sy = (r2[0][l] + r2[1][l] + r2[2][l] + r2[3][l]) / s;
  __syncthreads();
  float cxx = 0.f, cxy = 0.f, cyy = 0.f;
  #pragma unroll
  for (int j = 0; j < 12; ++j) {
    float dx = gxr[j] - sx, dy = gyr[j] - sy;
    cxx += le[j]*dx*dx; cxy += le[j]*dx*dy; cyy += le[j]*dy*dy;
  }
  r0[w][l] = cxx; r1[w][l] = cxy; r2[w][l] = cyy;
  __syncthreads();
  if (w == 0) {
    float c00 = (r0[0][l] + r0[1][l] + r0[2][l] + r0[3][l]) / s;
    float c01 = (r1[0][l] + r1[1][l] + r1[2][l] + r1[3][l]) / s;
    float c11 = (r2[0][l] + r2[1][l] + r2[2][l] + r2[3][l]) / s;
    float opl = x3[(size_t)DB*PIX + hw];
    float opac = 1.f / (1.f + expf(-opl));
    float a = c11*(1.f/9.f) + 0.3f;
    float b = c01*(1.f/9.f);
    float c = c00*(1.f/9.f) + 0.3f;
    float py = 50.f - sy;
    float px = 50.f - sx;
    float det = a*c - b*b;
    float op = (opac > 0.05f) ? opac : 0.f;
    float invd = 1.f;
    if (det > 0.f) invd = 1.f/det; else op = 0.f;
    float lop = (op > 0.f) ? logf(op) : -1e30f;
    int wid = n*PIX + hw;
    ((float4*)(ws + OFF_PRM))[wid]  = make_float4(py, px, -0.5f*c*invd, -0.5f*a*invd);
    ((float2*)(ws + OFF_PRM2))[wid] = make_float2(b*invd, lop);
  }
  float* ft = ws + OFF_FEATT;
  for (int half = 0; half < 2; ++half) {
    __syncthreads();
    int ch0 = half*64;
    #pragma unroll
    for (int r = 0; r < 16; ++r) {
      int ch = w*16 + r;
      tile[ch][l] = x3[(size_t)(DB + 1 + ch0 + ch)*PIX + hw];
    }
    __syncthreads();
    #pragma unroll
    for (int k = 0; k < 16; ++k) {
      int h = w + 4*k;
      ft[(size_t)(n*PIX + hw0 + h)*128 + ch0 + l] = tile[l][h];
    }
  }
}

template<int CTRL, int RMASK>
__device__ __forceinline__ float dpp_mul(float v) {
  int t = __builtin_amdgcn_update_dpp(0x3f800000, __float_as_int(v), CTRL, RMASK, 0xF, false);
  return v * __int_as_float(t);
}

// Split-K raster, NSPLIT=6 (11 groups/split, 16.9KB LDS). R22 config.
__global__ __launch_bounds__(512) void k_raster(const float* __restrict__ ws,
                                                float* __restrict__ wsout) {
  __shared__ float4 s4[SG];
  __shared__ float2 s2[SG];
  int lane = threadIdx.x & 63, wv = threadIdx.x >> 6;
  int split = blockIdx.x / 1250;
  int pxb   = blockIdx.x % 1250;
  int pix = pxb * 8 + wv;
  float yi = (float)(pix / 100), xi = (float)(pix % 100);
  int gbase = split * SG;
  const float4* prm4 = (const float4*)(ws + OFF_PRM) + gbase;
  const float2* prm2 = (const float2*)(ws + OFF_PRM2) + gbase;
  const float2* ft = (const float2*)(ws + OFF_FEATT);
  for (int i = threadIdx.x; i < SG; i += 512) {
    s4[i] = prm4[i];
    s2[i] = prm2[i];
  }
  __syncthreads();
  float T = 1.f, ax = 0.f, ay = 0.f;
  for (int gl = 0; gl < SG; gl += 64) {
    float4 c4 = s4[gl + lane];
    float2 c2 = s2[gl + lane];
    float dyv = c4.x - yi, dxv = c4.y - xi;
    float pw = c4.z*dyv*dyv + c4.w*dxv*dxv + c2.x*dyv*dxv;
    float t  = pw + c2.y;                       // pw + log(op)
    bool hit = (t >= TH_LOG);
    unsigned long long m0 = __ballot(hit);
    if (m0) {
      float alpha = __expf(fminf(t, c2.y));     // op*exp(min(pw,0))
      alpha = fminf(alpha, 0.99f);
      alpha = hit ? alpha : 0.f;
      float P = 1.f - alpha;
      P = dpp_mul<0x111, 0xF>(P);
      P = dpp_mul<0x112, 0xF>(P);
      P = dpp_mul<0x114, 0xF>(P);
      P = dpp_mul<0x118, 0xF>(P);
      P = dpp_mul<0x142, 0xA>(P);
      P = dpp_mul<0x143, 0xC>(P);
      float E = __int_as_float(__builtin_amdgcn_update_dpp(
                  0x3f800000, __float_as_int(P), 0x138, 0xF, 0xF, false));
      float w = alpha * T * E;
      T *= __int_as_float(__builtin_amdgcn_readlane(__float_as_int(P), 63));
      unsigned long long mask = __ballot(w > 1e-9f);
      int g0 = gbase + gl;
      while (mask) {
        int jj[8];
        #pragma unroll
        for (int b = 0; b < 8; ++b) {
          if (mask) { jj[b] = __builtin_ctzll(mask); mask &= mask - 1ull; }
          else jj[b] = -1;
        }
        float2 fb[8]; float wb[8];
        #pragma unroll
        for (int b = 0; b < 8; ++b) {
          int j = (jj[b] >= 0) ? jj[b] : jj[0];
          fb[b] = ft[(size_t)(g0 + j)*64 + lane];
          wb[b] = (jj[b] >= 0)
            ? __int_as_float(__builtin_amdgcn_readlane(__float_as_int(w), jj[b]))
            : 0.f;
        }
        #pragma unroll
        for (int b = 0; b < 8; ++b) { ax += wb[b]*fb[b].x; ay += wb[b]*fb[b].y; }
      }
      if (T < 1e-7f) break;                     // local exit (error < 1e-7)
    }
  }
  unsigned* sfu = (unsigned*)(wsout + OFF_SF);
  sfu[((size_t)split*BEVN + pix)*64 + lane] =
      (unsigned)f2bf(ax) | ((unsigned)f2bf(ay) << 16);
  if (lane == 0) (wsout + OFF_SP)[split*BEVN + pix] = T;
}

// ordered combine over 6 splits: F = sum_s (prod_{t<s} T_t) * F_s
__global__ __launch_bounds__(512) void k_combine(const float* __restrict__ ws,
                                                 float* __restrict__ out) {
  int lane = threadIdx.x & 63, wv = threadIdx.x >> 6;
  int pix = blockIdx.x * 8 + wv;
  const float* sp = ws + OFF_SP;
  const unsigned* sfu = (const unsigned*)(ws + OFF_SF);
  float T = 1.f, ox = 0.f, oy = 0.f;
  #pragma unroll
  for (int s = 0; s < NSPLIT; ++s) {
    unsigned u = sfu[((size_t)s*BEVN + pix)*64 + lane];
    ox += T * bf2f((unsigned short)(u & 0xffff));
    oy += T * bf2f((unsigned short)(u >> 16));
    T *= sp[s*BEVN + pix];
  }
  out[(size_t)(2*lane)*BEVN + pix]   = ox;
  out[(size_t)(2*lane+1)*BEVN + pix] = oy;
}

extern "C" void kernel_launch(void* const* d_in, const int* in_sizes, int n_in,
                              void* d_out, int out_size, void* d_ws, size_t ws_size,
                              hipStream_t stream) {
  const float* rot        = (const float*)d_in[0];
  const float* trans      = (const float*)d_in[1];
  const float* intr       = (const float*)d_in[2];
  const float* post_rot   = (const float*)d_in[3];
  const float* post_trans = (const float*)d_in[4];
  const float* img        = (const float*)d_in[5];
  const float* w1  = (const float*)d_in[6];
  const float* b1  = (const float*)d_in[7];
  const float* g1  = (const float*)d_in[8];
  const float* be1 = (const float*)d_in[9];
  const float* m1  = (const float*)d_in[10];
  const float* v1  = (const float*)d_in[11];
  const float* w2  = (const float*)d_in[12];
  const float* b2  = (const float*)d_in[13];
  const float* g2  = (const float*)d_in[14];
  const float* be2 = (const float*)d_in[15];
  const float* m2  = (const float*)d_in[16];
  const float* v2  = (const float*)d_in[17];
  const float* w3  = (const float*)d_in[18];
  const float* b3  = (const float*)d_in[19];
  float* ws  = (float*)d_ws;
  float* out = (float*)d_out;

  k_prep<<<3480, 256, 0, stream>>>(rot, intr, post_rot, trans, post_trans,
                                   w1, w2, w3, img, ws);

  // conv1: input imgbf (packed, in X2 slot), K=1152, KSPLIT=4
  k_gemm_mfma<<<dim3(11,2,24), 256, 0, stream>>>((unsigned*)(ws+OFF_X2), ws,
                                                 ws+OFF_PART, OFF_WT1);
  k_epi_bn<<<528, 256, 0, stream>>>(ws+OFF_PART, b1, g1, be1, m1, v1, ws+OFF_X1, 4);
  // conv2: input X1 packed; output X2 packed (overwrites dead imgbf)
  k_gemm_mfma<<<dim3(11,2,24), 256, 0, stream>>>((unsigned*)(ws+OFF_X1), ws,
                                                 ws+OFF_PART, OFF_WT2);
  k_epi_bn<<<528, 256, 0, stream>>>(ws+OFF_PART, b2, g2, be2, m2, v2, ws+OFF_X2, 4);
  // conv3: 1x1, K=128, bias fused, X3 f32
  k_gemm_mfma3<<<dim3(11,3,6), 256, 0, stream>>>((unsigned*)(ws+OFF_X2), ws,
                                                 b3, ws+OFF_X3);

  k_moments<<<66, 256, 0, stream>>>(ws);
  k_raster<<<7500, 512, 0, stream>>>(ws, ws);
  k_combine<<<1250, 512, 0, stream>>>(ws, out);
}

// Round 24
// 109.239 us; speedup vs baseline: 1.3019x; 1.0299x over previous
//
#include <hip/hip_runtime.h>
#include <math.h>

#define NCAM 6
#define FHh 16
#define FWw 44
#define PIX 704            // FHh*FWw
#define FCc 128
#define DB 48
#define C3 177             // DB + 1 + 128
#define KCONV 1152         // FCc*9
#define NG 4224            // NCAM*PIX
#define BEVN 10000
#define NSPLIT 6
#define SG 704             // gaussians per split (11 groups of 64)
#define TH_LOG (-5.5412635f)   // -ln(255): alpha>=1/255  <=>  pw+lop >= TH_LOG

// ---- ws layout (float offsets) ----
#define OFF_WT1    0                           // bf16 hi/lo ushorts (147456 floats)
#define OFF_WT2    147456
#define OFF_WT3    294912                      // bf16 hi/lo [192][128] (24576 floats)
#define OFF_GEO    319488                      // [6*48*704][2]
#define OFF_X1     724992                      // [6][128][704] packed uint hi|lo
#define OFF_X2     1265664                     // imgbf during conv1, then X2 packed
#define OFF_X3     1806336                     // [6][177][704] f32
#define OFF_PART   2553984                     // [4][6][128][704] conv partials
#define OFF_PRM    4716672                     // float4 [NG]: py,px,qc,qa
#define OFF_PRM2   4733568                     // float2 [NG]: qb,lop
#define OFF_FEATT  4742016                     // [NG][128] f32
#define OFF_SF     0                           // [NSPLIT][BEVN][64] uints (packed bf16 partials)
#define OFF_SP     3840000                     // [NSPLIT][BEVN] local transmittance
// end = 5,282,688 floats = 21.1 MiB

typedef __attribute__((ext_vector_type(8))) short bf16x8;
typedef __attribute__((ext_vector_type(4))) float f32x4;
typedef __attribute__((ext_vector_type(4))) int i32x4;

__device__ __forceinline__ unsigned short f2bf(float x) {
  unsigned u = __float_as_uint(x);
  return (unsigned short)((u + 0x7FFF + ((u >> 16) & 1)) >> 16);
}
__device__ __forceinline__ float bf2f(unsigned short h) {
  return __uint_as_float(((unsigned)h) << 16);
}
__device__ __forceinline__ unsigned packsplit(float x) {   // hi | lo<<16
  unsigned short h = f2bf(x);
  unsigned short l = f2bf(x - bf2f(h));
  return (unsigned)h | ((unsigned)l << 16);
}

__device__ __forceinline__ void inv3(const float* A, float* I) {
  float a=A[0],b=A[1],c=A[2],d=A[3],e=A[4],f=A[5],g=A[6],h=A[7],i=A[8];
  float c0 = e*i - f*h, c1 = f*g - d*i, c2 = d*h - e*g;
  float det = a*c0 + b*c1 + c*c2;
  float id = 1.f/det;
  I[0]=c0*id; I[1]=(c*h-b*i)*id; I[2]=(b*f-c*e)*id;
  I[3]=c1*id; I[4]=(a*i-c*g)*id; I[5]=(c*d-a*f)*id;
  I[6]=c2*id; I[7]=(b*g-a*h)*id; I[8]=(a*e-b*d)*id;
}

// fused: [0,792) geometry; [792,1368) weights; [1368,3480) img -> packed bf16
__global__ void k_prep(const float* __restrict__ rot, const float* __restrict__ intr,
                       const float* __restrict__ post_rot,
                       const float* __restrict__ trans, const float* __restrict__ post_trans,
                       const float* __restrict__ w1, const float* __restrict__ w2,
                       const float* __restrict__ w3, const float* __restrict__ img,
                       float* __restrict__ ws) {
  if (blockIdx.x < 792) {
    __shared__ float sm[NCAM][24];
    if (threadIdx.x < NCAM) {
      int n = threadIdx.x;
      float ip[9], ii[9];
      inv3(post_rot + n*9, ip);
      inv3(intr + n*9, ii);
      const float* R = rot + n*9;
      for (int j = 0; j < 9; ++j) sm[n][j] = ip[j];
      for (int r = 0; r < 3; ++r)
        for (int c = 0; c < 3; ++c) {
          float s = 0.f;
          for (int k = 0; k < 3; ++k) s += R[r*3+k]*ii[k*3+c];
          sm[n][9 + r*3 + c] = s;
        }
    }
    __syncthreads();
    int idx = blockIdx.x*256 + threadIdx.x;
    if (idx >= NCAM*DB*PIX) return;
    int n = idx / (DB*PIX);
    int rem = idx % (DB*PIX);
    int d = rem / PIX;
    int hw = rem % PIX;
    int h = hw / FWw, w = hw % FWw;
    float fx = w * (351.0f/43.0f);
    float fy = h * (127.0f/15.0f);
    float fz = 1.0f + (float)d;
    const float* pt = post_trans + n*3;
    float v0 = fx - pt[0], v1 = fy - pt[1], v2 = fz - pt[2];
    const float* m = sm[n];
    float x = m[0]*v0 + m[1]*v1 + m[2]*v2;
    float y = m[3]*v0 + m[4]*v1 + m[5]*v2;
    float z = m[6]*v0 + m[7]*v1 + m[8]*v2;
    float q0 = x*z, q1 = y*z, q2 = z;
    const float* c = m + 9;
    const float* t = trans + n*3;
    float gx = c[0]*q0 + c[1]*q1 + c[2]*q2 + t[0];
    float gy = c[3]*q0 + c[4]*q1 + c[5]*q2 + t[1];
    ((float2*)(ws + OFF_GEO))[idx] = make_float2(gx, gy);
  } else if (blockIdx.x < 1368) {
    int e = (blockIdx.x - 792)*256 + threadIdx.x;
    if (e < 147456) {
      float v1 = w1[e], v2 = w2[e];
      unsigned short h1 = f2bf(v1), h2 = f2bf(v2);
      unsigned short l1 = f2bf(v1 - bf2f(h1)), l2 = f2bf(v2 - bf2f(h2));
      unsigned short* wt1 = (unsigned short*)(ws + OFF_WT1);
      unsigned short* wt2 = (unsigned short*)(ws + OFF_WT2);
      wt1[e] = h1; wt1[147456 + e] = l1;
      wt2[e] = h2; wt2[147456 + e] = l2;
    }
    if (e < 192*128) {                   // conv3: [oc<192][k<128], zero-pad oc>=177
      int oc = e >> 7, k = e & 127;
      float v = (oc < C3) ? w3[oc*FCc + k] : 0.f;
      unsigned short h = f2bf(v);
      unsigned short* wt3 = (unsigned short*)(ws + OFF_WT3);
      wt3[e] = h; wt3[24576 + e] = f2bf(v - bf2f(h));
    }
  } else {
    int e = (blockIdx.x - 1368)*256 + threadIdx.x;
    if (e < NCAM*FCc*PIX)
      ((unsigned*)(ws + OFF_X2))[e] = packsplit(img[e]);   // imgbf in X2 slot
  }
}

#define LROW 20   // dwords per LDS row: 32 bf16 = 16 dw + 4 pad

// bf16x3 MFMA im2col GEMM, 3x3 convs. Packed bf16 input (hi|lo<<16).
__global__ __launch_bounds__(256) void k_gemm_mfma(
    const unsigned* __restrict__ in, const float* ws, float* __restrict__ part, int woff)
{
  __shared__ int alds[2][64*LROW];
  __shared__ int blds[2][64*LROW];
  int tid = threadIdx.x;
  int px0 = blockIdx.x * 64;
  int oc0 = blockIdx.y * 64;
  int z = blockIdx.z; int n = z >> 2, ks = z & 3;
  const unsigned short* whi = (const unsigned short*)(ws + woff);
  const unsigned short* wlo = whi + 147456;
  const unsigned* inn = in + (size_t)n*FCc*PIX;
  int wv = tid >> 6, lane = tid & 63;
  int a_oc = tid >> 2, a_kq = tid & 3;
  int b_px = tid & 63, b_kq = tid >> 6;
  int p = px0 + b_px; int b_y = p / FWw, b_x = p - b_y*FWw;
  int k00 = ks * 288;

  i32x4 pa_h, pa_l; unsigned bu[8];
  auto issueA = [&](int s) {
    size_t gi = (size_t)(oc0 + a_oc)*KCONV + (k00 + s*32 + a_kq*8);
    pa_h = *(const i32x4*)(whi + gi);
    pa_l = *(const i32x4*)(wlo + gi);
  };
  auto issueB = [&](int s) {
    #pragma unroll
    for (int j = 0; j < 8; ++j) {
      int k = k00 + s*32 + b_kq*8 + j;
      int ic = k / 9, tap = k - ic*9;
      int ky = tap / 3, kx = tap - ky*3;
      int yy = b_y + ky - 1, xx = b_x + kx - 1;
      unsigned v = 0u;
      if ((unsigned)yy < FHh && (unsigned)xx < FWw) v = inn[(size_t)ic*PIX + yy*FWw + xx];
      bu[j] = v;
    }
  };

  f32x4 a00 = {0.f,0.f,0.f,0.f}, a01 = a00, a10 = a00, a11 = a00;
  int ocr = (wv >> 1) * 32, pxr = (wv & 1) * 32;
  int dq = (lane >> 4) * 4;
  int rA0 = (ocr + (lane & 15)) * LROW + dq;
  int rA1 = rA0 + 16*LROW;
  int rB0 = (pxr + (lane & 15)) * LROW + dq;
  int rB1 = rB0 + 16*LROW;
  int aw = a_oc*LROW + a_kq*4;
  int bw = b_px*LROW + b_kq*4;

  issueA(0); issueB(0);
  for (int s = 0; s < 9; ++s) {
    __syncthreads();
    *(i32x4*)&alds[0][aw] = pa_h;
    *(i32x4*)&alds[1][aw] = pa_l;
    {
      i32x4 vh, vl;
      int th[8], tl[8];
      #pragma unroll
      for (int j = 0; j < 8; ++j) { th[j] = bu[j] & 0xffff; tl[j] = bu[j] >> 16; }
      vh.x = th[0]|(th[1]<<16); vh.y = th[2]|(th[3]<<16);
      vh.z = th[4]|(th[5]<<16); vh.w = th[6]|(th[7]<<16);
      vl.x = tl[0]|(tl[1]<<16); vl.y = tl[2]|(tl[3]<<16);
      vl.z = tl[4]|(tl[5]<<16); vl.w = tl[6]|(tl[7]<<16);
      *(i32x4*)&blds[0][bw] = vh;
      *(i32x4*)&blds[1][bw] = vl;
    }
    __syncthreads();
    if (s < 8) { issueA(s+1); issueB(s+1); }
    bf16x8 ah0 = *(bf16x8*)&alds[0][rA0], ah1 = *(bf16x8*)&alds[0][rA1];
    bf16x8 al0 = *(bf16x8*)&alds[1][rA0], al1 = *(bf16x8*)&alds[1][rA1];
    bf16x8 bh0 = *(bf16x8*)&blds[0][rB0], bh1 = *(bf16x8*)&blds[0][rB1];
    bf16x8 bl0 = *(bf16x8*)&blds[1][rB0], bl1 = *(bf16x8*)&blds[1][rB1];
    a00 = __builtin_amdgcn_mfma_f32_16x16x32_bf16(ah0, bh0, a00, 0, 0, 0);
    a01 = __builtin_amdgcn_mfma_f32_16x16x32_bf16(ah0, bh1, a01, 0, 0, 0);
    a10 = __builtin_amdgcn_mfma_f32_16x16x32_bf16(ah1, bh0, a10, 0, 0, 0);
    a11 = __builtin_amdgcn_mfma_f32_16x16x32_bf16(ah1, bh1, a11, 0, 0, 0);
    a00 = __builtin_amdgcn_mfma_f32_16x16x32_bf16(ah0, bl0, a00, 0, 0, 0);
    a01 = __builtin_amdgcn_mfma_f32_16x16x32_bf16(ah0, bl1, a01, 0, 0, 0);
    a10 = __builtin_amdgcn_mfma_f32_16x16x32_bf16(ah1, bl0, a10, 0, 0, 0);
    a11 = __builtin_amdgcn_mfma_f32_16x16x32_bf16(ah1, bl1, a11, 0, 0, 0);
    a00 = __builtin_amdgcn_mfma_f32_16x16x32_bf16(al0, bh0, a00, 0, 0, 0);
    a01 = __builtin_amdgcn_mfma_f32_16x16x32_bf16(al0, bh1, a01, 0, 0, 0);
    a10 = __builtin_amdgcn_mfma_f32_16x16x32_bf16(al1, bh0, a10, 0, 0, 0);
    a11 = __builtin_amdgcn_mfma_f32_16x16x32_bf16(al1, bh1, a11, 0, 0, 0);
  }
  float* pp = part + (size_t)(ks*NCAM + n)*FCc*PIX;
  int ocb = oc0 + ocr + ((lane >> 4) << 2);
  int pxb = px0 + pxr + (lane & 15);
  #pragma unroll
  for (int i = 0; i < 4; ++i) {
    pp[(size_t)(ocb + i)*PIX + pxb]           = a00[i];
    pp[(size_t)(ocb + i)*PIX + pxb + 16]      = a01[i];
    pp[(size_t)(ocb + 16 + i)*PIX + pxb]      = a10[i];
    pp[(size_t)(ocb + 16 + i)*PIX + pxb + 16] = a11[i];
  }
}

// bf16x3 MFMA GEMM for conv3 (1x1, K=128, bias fused, direct X3 f32 write).
__global__ __launch_bounds__(256) void k_gemm_mfma3(
    const unsigned* __restrict__ in, const float* ws,
    const float* __restrict__ bias, float* __restrict__ outbuf)
{
  __shared__ int alds[2][64*LROW];
  __shared__ int blds[2][64*LROW];
  int tid = threadIdx.x;
  int px0 = blockIdx.x * 64;
  int oc0 = blockIdx.y * 64;
  int n = blockIdx.z;
  const unsigned short* whi = (const unsigned short*)(ws + OFF_WT3);
  const unsigned short* wlo = whi + 24576;
  const unsigned* inn = in + (size_t)n*FCc*PIX;
  int wv = tid >> 6, lane = tid & 63;
  int a_oc = tid >> 2, a_kq = tid & 3;
  int b_px = tid & 63, b_kq = tid >> 6;
  int p = px0 + b_px;

  i32x4 pa_h, pa_l; unsigned bu[8];
  auto issueA = [&](int s) {
    size_t gi = (size_t)(oc0 + a_oc)*128 + (s*32 + a_kq*8);
    pa_h = *(const i32x4*)(whi + gi);
    pa_l = *(const i32x4*)(wlo + gi);
  };
  auto issueB = [&](int s) {
    #pragma unroll
    for (int j = 0; j < 8; ++j) {
      int ic = s*32 + b_kq*8 + j;
      bu[j] = inn[(size_t)ic*PIX + p];
    }
  };

  f32x4 a00 = {0.f,0.f,0.f,0.f}, a01 = a00, a10 = a00, a11 = a00;
  int ocr = (wv >> 1) * 32, pxr = (wv & 1) * 32;
  int dq = (lane >> 4) * 4;
  int rA0 = (ocr + (lane & 15)) * LROW + dq;
  int rA1 = rA0 + 16*LROW;
  int rB0 = (pxr + (lane & 15)) * LROW + dq;
  int rB1 = rB0 + 16*LROW;
  int aw = a_oc*LROW + a_kq*4;
  int bw = b_px*LROW + b_kq*4;

  issueA(0); issueB(0);
  for (int s = 0; s < 4; ++s) {
    __syncthreads();
    *(i32x4*)&alds[0][aw] = pa_h;
    *(i32x4*)&alds[1][aw] = pa_l;
    {
      i32x4 vh, vl;
      int th[8], tl[8];
      #pragma unroll
      for (int j = 0; j < 8; ++j) { th[j] = bu[j] & 0xffff; tl[j] = bu[j] >> 16; }
      vh.x = th[0]|(th[1]<<16); vh.y = th[2]|(th[3]<<16);
      vh.z = th[4]|(th[5]<<16); vh.w = th[6]|(th[7]<<16);
      vl.x = tl[0]|(tl[1]<<16); vl.y = tl[2]|(tl[3]<<16);
      vl.z = tl[4]|(tl[5]<<16); vl.w = tl[6]|(tl[7]<<16);
      *(i32x4*)&blds[0][bw] = vh;
      *(i32x4*)&blds[1][bw] = vl;
    }
    __syncthreads();
    if (s < 3) { issueA(s+1); issueB(s+1); }
    bf16x8 ah0 = *(bf16x8*)&alds[0][rA0], ah1 = *(bf16x8*)&alds[0][rA1];
    bf16x8 al0 = *(bf16x8*)&alds[1][rA0], al1 = *(bf16x8*)&alds[1][rA1];
    bf16x8 bh0 = *(bf16x8*)&blds[0][rB0], bh1 = *(bf16x8*)&blds[0][rB1];
    bf16x8 bl0 = *(bf16x8*)&blds[1][rB0], bl1 = *(bf16x8*)&blds[1][rB1];
    a00 = __builtin_amdgcn_mfma_f32_16x16x32_bf16(ah0, bh0, a00, 0, 0, 0);
    a01 = __builtin_amdgcn_mfma_f32_16x16x32_bf16(ah0, bh1, a01, 0, 0, 0);
    a10 = __builtin_amdgcn_mfma_f32_16x16x32_bf16(ah1, bh0, a10, 0, 0, 0);
    a11 = __builtin_amdgcn_mfma_f32_16x16x32_bf16(ah1, bh1, a11, 0, 0, 0);
    a00 = __builtin_amdgcn_mfma_f32_16x16x32_bf16(ah0, bl0, a00, 0, 0, 0);
    a01 = __builtin_amdgcn_mfma_f32_16x16x32_bf16(ah0, bl1, a01, 0, 0, 0);
    a10 = __builtin_amdgcn_mfma_f32_16x16x32_bf16(ah1, bl0, a10, 0, 0, 0);
    a11 = __builtin_amdgcn_mfma_f32_16x16x32_bf16(ah1, bl1, a11, 0, 0, 0);
    a00 = __builtin_amdgcn_mfma_f32_16x16x32_bf16(al0, bh0, a00, 0, 0, 0);
    a01 = __builtin_amdgcn_mfma_f32_16x16x32_bf16(al0, bh1, a01, 0, 0, 0);
    a10 = __builtin_amdgcn_mfma_f32_16x16x32_bf16(al1, bh0, a10, 0, 0, 0);
    a11 = __builtin_amdgcn_mfma_f32_16x16x32_bf16(al1, bh1, a11, 0, 0, 0);
  }
  int ocb = oc0 + ocr + ((lane >> 4) << 2);
  int pxb = px0 + pxr + (lane & 15);
  #pragma unroll
  for (int i = 0; i < 4; ++i) {
    int o0 = ocb + i, o1 = ocb + 16 + i;
    if (o0 < C3) {
      float b = bias[o0];
      outbuf[(size_t)(n*C3 + o0)*PIX + pxb]      = a00[i] + b;
      outbuf[(size_t)(n*C3 + o0)*PIX + pxb + 16] = a01[i] + b;
    }
    if (o1 < C3) {
      float b = bias[o1];
      outbuf[(size_t)(n*C3 + o1)*PIX + pxb]      = a10[i] + b;
      outbuf[(size_t)(n*C3 + o1)*PIX + pxb + 16] = a11[i] + b;
    }
  }
}

// epilogue: KSPLIT reduce + BN + ReLU, output PACKED bf16 (hi|lo<<16)
__global__ void k_epi_bn(const float* __restrict__ part, const float* __restrict__ cb,
                         const float* __restrict__ g, const float* __restrict__ be,
                         const float* __restrict__ mn, const float* __restrict__ vr,
                         float* __restrict__ out, int KSPLIT)
{
  int idx = blockIdx.x*256 + threadIdx.x;
  if (idx >= NCAM*FCc*176) return;
  int px4 = idx % 176;
  int t = idx / 176;
  int oc = t % FCc;
  int n = t / FCc;
  float4 s = {0.f,0.f,0.f,0.f};
  for (int ks = 0; ks < KSPLIT; ++ks) {
    const float4* p = (const float4*)(part + (size_t)((ks*NCAM+n)*FCc + oc)*PIX);
    float4 v = p[px4];
    s.x += v.x; s.y += v.y; s.z += v.z; s.w += v.w;
  }
  float inv = g[oc] * rsqrtf(vr[oc] + 1e-3f);
  float sh = (cb[oc] - mn[oc]) * inv + be[oc];
  uint4 o;
  o.x = packsplit(fmaxf(s.x*inv + sh, 0.f));
  o.y = packsplit(fmaxf(s.y*inv + sh, 0.f));
  o.z = packsplit(fmaxf(s.z*inv + sh, 0.f));
  o.w = packsplit(fmaxf(s.w*inv + sh, 0.f));
  ((uint4*)((unsigned*)out + (size_t)(n*FCc + oc)*PIX))[px4] = o;
}

// Coalesced moments (R21): block = 64 hw x 4 waves (lane = hw).
__global__ __launch_bounds__(256) void k_moments(float* __restrict__ ws) {
  __shared__ float r0[4][64], r1[4][64], r2[4][64];
  __shared__ float tile[64][65];
  int tid = threadIdx.x;
  int w = tid >> 6, l = tid & 63;
  int n = blockIdx.x / 11, hw0 = (blockIdx.x % 11) * 64;
  int hw = hw0 + l;
  const float* x3 = ws + OFF_X3 + (size_t)n*C3*PIX;
  const float2* geo = (const float2*)(ws + OFF_GEO);
  float le[12], gxr[12], gyr[12];
  float pm = -1e30f;
  #pragma unroll
  for (int j = 0; j < 12; ++j) {
    le[j] = x3[(size_t)(w*12 + j)*PIX + hw];
    pm = fmaxf(pm, le[j]);
  }
  r0[w][l] = pm;
  __syncthreads();
  float mx = fmaxf(fmaxf(r0[0][l], r0[1][l]), fmaxf(r0[2][l], r0[3][l]));
  __syncthreads();
  float s_p = 0.f, sx_p = 0.f, sy_p = 0.f;
  #pragma unroll
  for (int j = 0; j < 12; ++j) {
    float e = expf(le[j] - mx);
    le[j] = e;
    float2 g2 = geo[(size_t)(n*DB + w*12 + j)*PIX + hw];
    gxr[j] = g2.x; gyr[j] = g2.y;
    s_p += e; sx_p += e*g2.x; sy_p += e*g2.y;
  }
  r0[w][l] = s_p; r1[w][l] = sx_p; r2[w][l] = sy_p;
  __syncthreads();
  float s  = r0[0][l] + r0[1][l] + r0[2][l] + r0[3][l];
  float sx = (r1[0][l] + r1[1][l] + r1[2][l] + r1[3][l]) / s;
  float sy = (r2[0][l] + r2[1][l] + r2[2][l] + r2[3][l]) / s;
  __syncthreads();
  float cxx = 0.f, cxy = 0.f, cyy = 0.f;
  #pragma unroll
  for (int j = 0; j < 12; ++j) {
    float dx = gxr[j] - sx, dy = gyr[j] - sy;
    cxx += le[j]*dx*dx; cxy += le[j]*dx*dy; cyy += le[j]*dy*dy;
  }
  r0[w][l] = cxx; r1[w][l] = cxy; r2[w][l] = cyy;
  __syncthreads();
  if (w == 0) {
    float c00 = (r0[0][l] + r0[1][l] + r0[2][l] + r0[3][l]) / s;
    float c01 = (r1[0][l] + r1[1][l] + r1[2][l] + r1[3][l]) / s;
    float c11 = (r2[0][l] + r2[1][l] + r2[2][l] + r2[3][l]) / s;
    float opl = x3[(size_t)DB*PIX + hw];
    float opac = 1.f / (1.f + expf(-opl));
    float a = c11*(1.f/9.f) + 0.3f;
    float b = c01*(1.f/9.f);
    float c = c00*(1.f/9.f) + 0.3f;
    float py = 50.f - sy;
    float px = 50.f - sx;
    float det = a*c - b*b;
    float op = (opac > 0.05f) ? opac : 0.f;
    float invd = 1.f;
    if (det > 0.f) invd = 1.f/det; else op = 0.f;
    float lop = (op > 0.f) ? logf(op) : -1e30f;
    int wid = n*PIX + hw;
    ((float4*)(ws + OFF_PRM))[wid]  = make_float4(py, px, -0.5f*c*invd, -0.5f*a*invd);
    ((float2*)(ws + OFF_PRM2))[wid] = make_float2(b*invd, lop);
  }
  float* ft = ws + OFF_FEATT;
  for (int half = 0; half < 2; ++half) {
    __syncthreads();
    int ch0 = half*64;
    #pragma unroll
    for (int r = 0; r < 16; ++r) {
      int ch = w*16 + r;
      tile[ch][l] = x3[(size_t)(DB + 1 + ch0 + ch)*PIX + hw];
    }
    __syncthreads();
    #pragma unroll
    for (int k = 0; k < 16; ++k) {
      int h = w + 4*k;
      ft[(size_t)(n*PIX + hw0 + h)*128 + ch0 + l] = tile[l][h];
    }
  }
}

template<int CTRL, int RMASK>
__device__ __forceinline__ float dpp_mul(float v) {
  int t = __builtin_amdgcn_update_dpp(0x3f800000, __float_as_int(v), CTRL, RMASK, 0xF, false);
  return v * __int_as_float(t);
}
__device__ __forceinline__ float scan_prod(float P) {
  P = dpp_mul<0x111, 0xF>(P);
  P = dpp_mul<0x112, 0xF>(P);
  P = dpp_mul<0x114, 0xF>(P);
  P = dpp_mul<0x118, 0xF>(P);
  P = dpp_mul<0x142, 0xA>(P);
  P = dpp_mul<0x143, 0xC>(P);
  return P;                      // inclusive prefix product
}
__device__ __forceinline__ float excl_shift(float P) {
  return __int_as_float(__builtin_amdgcn_update_dpp(
           0x3f800000, __float_as_int(P), 0x138, 0xF, 0xF, false));
}

// Split-K raster, NSPLIT=6, PAIRED-GROUP ILP: groups (g,g+1) evaluated and
// scanned together (independent chains interleave -> DPP-chain stalls halve);
// only the final w/T scalars are serial. Same math, same order, bit-identical.
__global__ __launch_bounds__(512) void k_raster(const float* __restrict__ ws,
                                                float* __restrict__ wsout) {
  __shared__ float4 s4[SG];
  __shared__ float2 s2[SG];
  int lane = threadIdx.x & 63, wv = threadIdx.x >> 6;
  int split = blockIdx.x / 1250;
  int pxb   = blockIdx.x % 1250;
  int pix = pxb * 8 + wv;
  float yi = (float)(pix / 100), xi = (float)(pix % 100);
  int gbase = split * SG;
  const float4* prm4 = (const float4*)(ws + OFF_PRM) + gbase;
  const float2* prm2 = (const float2*)(ws + OFF_PRM2) + gbase;
  const float2* ft = (const float2*)(ws + OFF_FEATT);
  for (int i = threadIdx.x; i < SG; i += 512) {
    s4[i] = prm4[i];
    s2[i] = prm2[i];
  }
  __syncthreads();
  float T = 1.f, ax = 0.f, ay = 0.f;

  auto gather = [&](unsigned long long mask, float w, int g0) {
    while (mask) {
      int jj[8];
      #pragma unroll
      for (int b = 0; b < 8; ++b) {
        if (mask) { jj[b] = __builtin_ctzll(mask); mask &= mask - 1ull; }
        else jj[b] = -1;
      }
      float2 fb[8]; float wb[8];
      #pragma unroll
      for (int b = 0; b < 8; ++b) {
        int j = (jj[b] >= 0) ? jj[b] : jj[0];
        fb[b] = ft[(size_t)(g0 + j)*64 + lane];
        wb[b] = (jj[b] >= 0)
          ? __int_as_float(__builtin_amdgcn_readlane(__float_as_int(w), jj[b]))
          : 0.f;
      }
      #pragma unroll
      for (int b = 0; b < 8; ++b) { ax += wb[b]*fb[b].x; ay += wb[b]*fb[b].y; }
    }
  };

  // 5 pairs (groups 0..9)
  for (int gl = 0; gl + 128 <= SG; gl += 128) {
    float4 c4a = s4[gl + lane];        float2 c2a = s2[gl + lane];
    float4 c4b = s4[gl + 64 + lane];   float2 c2b = s2[gl + 64 + lane];
    float dya = c4a.x - yi, dxa = c4a.y - xi;
    float dyb = c4b.x - yi, dxb = c4b.y - xi;
    float ta = c4a.z*dya*dya + c4a.w*dxa*dxa + c2a.x*dya*dxa + c2a.y;
    float tb = c4b.z*dyb*dyb + c4b.w*dxb*dxb + c2b.x*dyb*dxb + c2b.y;
    bool hita = (ta >= TH_LOG), hitb = (tb >= TH_LOG);
    unsigned long long m0a = __ballot(hita);
    unsigned long long m0b = __ballot(hitb);
    if (m0a | m0b) {
      float aa = fminf(__expf(fminf(ta, c2a.y)), 0.99f); aa = hita ? aa : 0.f;
      float ab = fminf(__expf(fminf(tb, c2b.y)), 0.99f); ab = hitb ? ab : 0.f;
      float Pa = scan_prod(1.f - aa);          // two independent chains:
      float Pb = scan_prod(1.f - ab);          // compiler interleaves
      float Ea = excl_shift(Pa);
      float Eb = excl_shift(Pb);
      float wa = aa * T * Ea;
      float T1 = T * __int_as_float(__builtin_amdgcn_readlane(__float_as_int(Pa), 63));
      float wb = ab * T1 * Eb;
      T = T1 * __int_as_float(__builtin_amdgcn_readlane(__float_as_int(Pb), 63));
      gather(__ballot(wa > 1e-9f), wa, gbase + gl);
      gather(__ballot(wb > 1e-9f), wb, gbase + gl + 64);
      if (T < 1e-7f) break;                    // pair-granular exit
    }
  }
  // tail group 10 (gl = 640), only if not saturated
  if (T >= 1e-7f) {
    int gl = SG - 64;
    float4 c4 = s4[gl + lane];
    float2 c2 = s2[gl + lane];
    float dyv = c4.x - yi, dxv = c4.y - xi;
    float t = c4.z*dyv*dyv + c4.w*dxv*dxv + c2.x*dyv*dxv + c2.y;
    bool hit = (t >= TH_LOG);
    unsigned long long m0 = __ballot(hit);
    if (m0) {
      float alpha = fminf(__expf(fminf(t, c2.y)), 0.99f); alpha = hit ? alpha : 0.f;
      float P = scan_prod(1.f - alpha);
      float E = excl_shift(P);
      float w = alpha * T * E;
      T *= __int_as_float(__builtin_amdgcn_readlane(__float_as_int(P), 63));
      gather(__ballot(w > 1e-9f), w, gbase + gl);
    }
  }
  unsigned* sfu = (unsigned*)(wsout + OFF_SF);
  sfu[((size_t)split*BEVN + pix)*64 + lane] =
      (unsigned)f2bf(ax) | ((unsigned)f2bf(ay) << 16);
  if (lane == 0) (wsout + OFF_SP)[split*BEVN + pix] = T;
}

// ordered combine over 6 splits: F = sum_s (prod_{t<s} T_t) * F_s
__global__ __launch_bounds__(512) void k_combine(const float* __restrict__ ws,
                                                 float* __restrict__ out) {
  int lane = threadIdx.x & 63, wv = threadIdx.x >> 6;
  int pix = blockIdx.x * 8 + wv;
  const float* sp = ws + OFF_SP;
  const unsigned* sfu = (const unsigned*)(ws + OFF_SF);
  float T = 1.f, ox = 0.f, oy = 0.f;
  #pragma unroll
  for (int s = 0; s < NSPLIT; ++s) {
    unsigned u = sfu[((size_t)s*BEVN + pix)*64 + lane];
    ox += T * bf2f((unsigned short)(u & 0xffff));
    oy += T * bf2f((unsigned short)(u >> 16));
    T *= sp[s*BEVN + pix];
  }
  out[(size_t)(2*lane)*BEVN + pix]   = ox;
  out[(size_t)(2*lane+1)*BEVN + pix] = oy;
}

extern "C" void kernel_launch(void* const* d_in, const int* in_sizes, int n_in,
                              void* d_out, int out_size, void* d_ws, size_t ws_size,
                              hipStream_t stream) {
  const float* rot        = (const float*)d_in[0];
  const float* trans      = (const float*)d_in[1];
  const float* intr       = (const float*)d_in[2];
  const float* post_rot   = (const float*)d_in[3];
  const float* post_trans = (const float*)d_in[4];
  const float* img        = (const float*)d_in[5];
  const float* w1  = (const float*)d_in[6];
  const float* b1  = (const float*)d_in[7];
  const float* g1  = (const float*)d_in[8];
  const float* be1 = (const float*)d_in[9];
  const float* m1  = (const float*)d_in[10];
  const float* v1  = (const float*)d_in[11];
  const float* w2  = (const float*)d_in[12];
  const float* b2  = (const float*)d_in[13];
  const float* g2  = (const float*)d_in[14];
  const float* be2 = (const float*)d_in[15];
  const float* m2  = (const float*)d_in[16];
  const float* v2  = (const float*)d_in[17];
  const float* w3  = (const float*)d_in[18];
  const float* b3  = (const float*)d_in[19];
  float* ws  = (float*)d_ws;
  float* out = (float*)d_out;

  k_prep<<<3480, 256, 0, stream>>>(rot, intr, post_rot, trans, post_trans,
                                   w1, w2, w3, img, ws);

  // conv1: input imgbf (packed, in X2 slot), K=1152, KSPLIT=4
  k_gemm_mfma<<<dim3(11,2,24), 256, 0, stream>>>((unsigned*)(ws+OFF_X2), ws,
                                                 ws+OFF_PART, OFF_WT1);
  k_epi_bn<<<528, 256, 0, stream>>>(ws+OFF_PART, b1, g1, be1, m1, v1, ws+OFF_X1, 4);
  // conv2: input X1 packed; output X2 packed (overwrites dead imgbf)
  k_gemm_mfma<<<dim3(11,2,24), 256, 0, stream>>>((unsigned*)(ws+OFF_X1), ws,
                                                 ws+OFF_PART, OFF_WT2);
  k_epi_bn<<<528, 256, 0, stream>>>(ws+OFF_PART, b2, g2, be2, m2, v2, ws+OFF_X2, 4);
  // conv3: 1x1, K=128, bias fused, X3 f32
  k_gemm_mfma3<<<dim3(11,3,6), 256, 0, stream>>>((unsigned*)(ws+OFF_X2), ws,
                                                 b3, ws+OFF_X3);

  k_moments<<<66, 256, 0, stream>>>(ws);
  k_raster<<<7500, 512, 0, stream>>>(ws, ws);
  k_combine<<<1250, 512, 0, stream>>>(ws, out);
}